// Round 8
// baseline (222.323 us; speedup 1.0000x reference)
//
#include <hip/hip_runtime.h>
#include <hip/hip_bf16.h>

typedef unsigned short u16;
typedef unsigned int u32;
typedef __bf16 bf16_t;
typedef bf16_t bf16x8 __attribute__((ext_vector_type(8)));
typedef float fx4 __attribute__((ext_vector_type(4)));

#define TT 2048
#define HH 8
#define KK 64
#define VV 192
#define CC 1536
#define SPLITS 3
#define LOG2E 1.4426950408889634f

__device__ __forceinline__ float bf2f(u16 b) {
  union { u32 u; float f; } v; v.u = ((u32)b) << 16; return v.f;
}
__device__ __forceinline__ u16 f2bf(float f) {
  union { float f; u32 u; } v; v.f = f;
  return (u16)((v.u + 0x7FFFu + ((v.u >> 16) & 1u)) >> 16);
}
__device__ __forceinline__ fx4 mfma16(bf16x8 a, bf16x8 b, fx4 c) {
  return __builtin_amdgcn_mfma_f32_16x16x32_bf16(a, b, c, 0, 0, 0);
}
// async global->LDS, 16B/lane; LDS dest = wave-uniform base, lane*16 implicit
__device__ __forceinline__ void gl_lds16(const u16* g, u16* l) {
  __builtin_amdgcn_global_load_lds(
      (const __attribute__((address_space(1))) u32*)g,
      (__attribute__((address_space(3))) u32*)l, 16, 0, 0);
}

// ------ prep: weight transposes + cidx/WrT/dW tables + x conversion ----------
// z=0..3: weight transposes; z=4 (block 0,0): tables; z=5: x f32->bf16.
__global__ __launch_bounds__(256) void prep_kernel(
    const float* __restrict__ Wq, const float* __restrict__ Wk,
    const float* __restrict__ Wv, const float* __restrict__ Wo,
    const float* __restrict__ x, const float* __restrict__ Wr,
    const float* __restrict__ rwb, const float* __restrict__ rrb,
    u16* __restrict__ WqT, u16* __restrict__ WkT,
    u16* __restrict__ WvT, u16* __restrict__ WoT,
    u16* __restrict__ xbf, unsigned char* __restrict__ cidx_g,
    u16* __restrict__ WrT, float* __restrict__ dW) {
  const int z = blockIdx.z;
  const int t = threadIdx.x;
  if (z == 4) {
    if (blockIdx.x != 0 || blockIdx.y != 0) return;
    // cidx: borzoi center-width category per |distance|
    float pr = expf(logf((float)(TT + 1)) / 16.0f);
    float cw[16];
    float wv = pr;
    for (int i = 0; i < 16; ++i) { cw[i] = wv - 1.0f; wv *= pr; }
    for (int idx = t; idx < TT; idx += 256) {
      int c = 15;
      for (int i = 14; i >= 0; --i)
        if (cw[i] > (float)idx) c = i;
      cidx_g[idx] = (unsigned char)c;
    }
    // WrT[h][i][k] bf16 from Wr f32 [32][512]
    for (int idx = t; idx < 8 * 32 * 64; idx += 256) {
      int hh = idx >> 11, rem = idx & 2047;
      int i = rem >> 6, k = rem & 63;
      WrT[idx] = f2bf(Wr[i * 512 + hh * 64 + k]);
    }
    // dW[h*32+i] = sum_k (rrb - rwb)[h*64+k] * Wr[i][h*64+k]  (log2e-scaled)
    {
      int hh = t >> 5, i = t & 31;
      float s = 0.0f;
      for (int k = 0; k < 64; ++k)
        s += (rrb[hh * 64 + k] - rwb[hh * 64 + k]) * Wr[i * 512 + hh * 64 + k];
      dW[t] = s * LOG2E;
    }
    return;
  }
  if (z == 5) {
    const size_t ngroups = (size_t)TT * CC / 8;
    int bid = blockIdx.y * 24 + blockIdx.x;  // 0..575
    for (size_t g = (size_t)bid * 256 + t; g < ngroups; g += (size_t)576 * 256) {
      size_t i = g * 8;
      float4 f0 = *(const float4*)&x[i];
      float4 f1 = *(const float4*)&x[i + 4];
      union { u16 h[8]; uint4 v; } pk;
      pk.h[0] = f2bf(f0.x); pk.h[1] = f2bf(f0.y);
      pk.h[2] = f2bf(f0.z); pk.h[3] = f2bf(f0.w);
      pk.h[4] = f2bf(f1.x); pk.h[5] = f2bf(f1.y);
      pk.h[6] = f2bf(f1.z); pk.h[7] = f2bf(f1.w);
      *(uint4*)&xbf[i] = pk.v;
    }
    return;
  }
  if (z < 2 && blockIdx.x >= 8) return;
  const float* in = (z == 0) ? Wq : (z == 1) ? Wk : (z == 2) ? Wv : Wo;
  u16* out = (z == 0) ? WqT : (z == 1) ? WkT : (z == 2) ? WvT : WoT;
  const int in_rs = (z < 2) ? 512 : 1536;
  const int out_rs = 1536;

  __shared__ u16 tile[64][68];
  const int c0 = blockIdx.x * 64, r0 = blockIdx.y * 64;
#pragma unroll
  for (int i = 0; i < 4; ++i) {
    int idx = i * 256 + t;
    int r = idx >> 4, ch = idx & 15;
    float4 fv = *(const float4*)&in[(size_t)(r0 + r) * in_rs + c0 + ch * 4];
    tile[r][ch * 4 + 0] = f2bf(fv.x);
    tile[r][ch * 4 + 1] = f2bf(fv.y);
    tile[r][ch * 4 + 2] = f2bf(fv.z);
    tile[r][ch * 4 + 3] = f2bf(fv.w);
  }
  __syncthreads();
#pragma unroll
  for (int i = 0; i < 4; ++i) {
    int idx = i * 256 + t;
    int r = idx >> 4, ch = idx & 15;
    u16 a0 = tile[ch * 4 + 0][r], a1 = tile[ch * 4 + 1][r];
    u16 a2 = tile[ch * 4 + 2][r], a3 = tile[ch * 4 + 3][r];
    uint2 d;
    d.x = (u32)a0 | ((u32)a1 << 16);
    d.y = (u32)a2 | ((u32)a3 << 16);
    *(uint2*)&out[(size_t)(c0 + r) * out_rs + r0 + ch * 4] = d;
  }
}

// ---------------- unified QKV projection GEMM (bf16 A) -----------------------
// BM=128 BN=64 BK=64, 3-buffer LDS rotation + counted vmcnt pipeline (T3/T4):
// wait vmcnt(6) = current buffer's 6 loads done, next buffer's 6 in flight;
// stage k+2 each step -> staging latency spans 2 full k-steps, never drained
// to 0 in the main loop. LDS 72KB -> 2 blocks/CU.
// grid (40,16): cb<8 -> Q (scale+bias, log2e), cb<16 -> K, else V (vT write).
__global__ __launch_bounds__(256) void gemm_qkv(
    const u16* __restrict__ xbf, const u16* __restrict__ WqT,
    const u16* __restrict__ WkT, const u16* __restrict__ WvT,
    u16* __restrict__ qw, u16* __restrict__ Kws, u16* __restrict__ vTw,
    const float* __restrict__ rwb) {
  __shared__ u16 As[3 * 128 * 64];  // 3 x 16 KB
  __shared__ u16 Bs[3 * 64 * 64];   // 3 x  8 KB
  const int cb = blockIdx.x;
  const u16* BT = (cb < 8) ? WqT : (cb < 16) ? WkT : WvT;
  const int n0 = ((cb < 8) ? cb : (cb < 16) ? cb - 8 : cb - 16) * 64;
  const int t = threadIdx.x;
  const int lane = t & 63, wid = t >> 6;
  const int l16 = lane & 15, quad = lane >> 4;
  const int wm = wid >> 1, wn = wid & 1;
  const int m0 = blockIdx.y * 128;
  const int wbase = wid * 512;  // wave-uniform LDS chunk base (u16 idx)

  fx4 acc[4][2] = {};

  auto stage = [&](int p, int k0) {
#pragma unroll
    for (int i = 0; i < 4; ++i) {
      int chunk = i * 256 + t;
      int r = chunk >> 3, c = (chunk & 7) ^ (r & 7);
      gl_lds16(&xbf[(size_t)(m0 + r) * CC + k0 + c * 8],
               &As[p * 8192 + i * 2048 + wbase]);
    }
#pragma unroll
    for (int i = 0; i < 2; ++i) {
      int chunk = i * 256 + t;
      int r = chunk >> 3, c = (chunk & 7) ^ (r & 7);
      gl_lds16(&BT[(size_t)(n0 + r) * CC + k0 + c * 8],
               &Bs[p * 4096 + i * 2048 + wbase]);
    }
  };
  auto compute = [&](int p) {
#pragma unroll
    for (int ks = 0; ks < 2; ++ks) {
      bf16x8 af[4], bfr[2];
#pragma unroll
      for (int mi = 0; mi < 4; ++mi) {
        int Ra = wm * 64 + mi * 16 + l16;
        af[mi] = *(const bf16x8*)&As[p * 8192 + Ra * 64 + (((ks * 4 + quad) ^ (Ra & 7))) * 8];
      }
#pragma unroll
      for (int ni = 0; ni < 2; ++ni) {
        int Rb = wn * 32 + ni * 16 + l16;
        bfr[ni] = *(const bf16x8*)&Bs[p * 4096 + Rb * 64 + (((ks * 4 + quad) ^ (Rb & 7))) * 8];
      }
#pragma unroll
      for (int mi = 0; mi < 4; ++mi)
#pragma unroll
        for (int ni = 0; ni < 2; ++ni)
          acc[mi][ni] = mfma16(af[mi], bfr[ni], acc[mi][ni]);
    }
  };

  stage(0, 0);
  stage(1, 64);
  int cur = 0;
  for (int kt = 0; kt < 22; ++kt) {
    asm volatile("s_waitcnt vmcnt(6)" ::: "memory");  // cur's loads done
    __builtin_amdgcn_s_barrier();
    __builtin_amdgcn_sched_barrier(0);
    int nxt2 = cur + 2; if (nxt2 >= 3) nxt2 -= 3;
    stage(nxt2, (kt + 2) * 64);   // target consumed at kt-1 (barrier-protected)
    compute(cur);
    asm volatile("s_waitcnt lgkmcnt(0)" ::: "memory");  // ds_reads drained
    __builtin_amdgcn_s_barrier();                       // before restage at kt+1
    cur = (cur == 2) ? 0 : cur + 1;
  }
  // kt=22: buffer cur=1; S23's 6 loads still in flight
  asm volatile("s_waitcnt vmcnt(6)" ::: "memory");
  __builtin_amdgcn_s_barrier();
  __builtin_amdgcn_sched_barrier(0);
  compute(cur);
  cur = (cur == 2) ? 0 : cur + 1;
  // kt=23: buffer 2
  asm volatile("s_waitcnt vmcnt(0)" ::: "memory");
  __builtin_amdgcn_s_barrier();
  __builtin_amdgcn_sched_barrier(0);
  compute(cur);

#pragma unroll
  for (int mi = 0; mi < 4; ++mi)
#pragma unroll
    for (int ni = 0; ni < 2; ++ni) {
      int col = n0 + wn * 32 + ni * 16 + l16;
      int row0 = m0 + wm * 64 + mi * 16 + quad * 4;
      if (cb < 16) {
        int h = col >> 6, kx = col & 63;
#pragma unroll
        for (int r = 0; r < 4; ++r) {
          float v = acc[mi][ni][r];
          size_t o = ((size_t)h * TT + row0 + r) * 64 + kx;
          if (cb < 8) qw[o] = f2bf((v * 0.125f + rwb[col]) * LOG2E);
          else Kws[o] = f2bf(v);
        }
      } else {
        // direct transposed V write: vTw[h][vv][t], 4 consecutive t per lane
        // col is ALREADY rebased to [0,1536) via n0 = (cb-16)*64.
        int h = col / 192, vv = col - h * 192;
        union { u16 h4[4]; uint2 v2; } pk;
#pragma unroll
        for (int r = 0; r < 4; ++r) pk.h4[r] = f2bf(acc[mi][ni][r]);
        *(uint2*)&vTw[(size_t)h * VV * TT + (size_t)vv * TT + row0] = pk.v2;
      }
    }
}

// ---------------- out-projection GEMM: FLOAT out = A@WoT^T + bias ------------
// Same 3-buffer counted-vmcnt pipeline as gemm_qkv. grid (24,16).
__global__ __launch_bounds__(256) void gemm_out(
    const u16* __restrict__ A, const u16* __restrict__ BT,
    float* __restrict__ out0, const float* __restrict__ bias0) {
  __shared__ u16 As[3 * 128 * 64];
  __shared__ u16 Bs[3 * 64 * 64];
  const int t = threadIdx.x;
  const int lane = t & 63, wid = t >> 6;
  const int l16 = lane & 15, quad = lane >> 4;
  const int wm = wid >> 1, wn = wid & 1;
  const int m0 = blockIdx.y * 128, n0 = blockIdx.x * 64;
  const int wbase = wid * 512;

  fx4 acc[4][2] = {};

  auto stage = [&](int p, int k0) {
#pragma unroll
    for (int i = 0; i < 4; ++i) {
      int chunk = i * 256 + t;
      int r = chunk >> 3, c = (chunk & 7) ^ (r & 7);
      gl_lds16(&A[(size_t)(m0 + r) * CC + k0 + c * 8],
               &As[p * 8192 + i * 2048 + wbase]);
    }
#pragma unroll
    for (int i = 0; i < 2; ++i) {
      int chunk = i * 256 + t;
      int r = chunk >> 3, c = (chunk & 7) ^ (r & 7);
      gl_lds16(&BT[(size_t)(n0 + r) * CC + k0 + c * 8],
               &Bs[p * 4096 + i * 2048 + wbase]);
    }
  };
  auto compute = [&](int p) {
#pragma unroll
    for (int ks = 0; ks < 2; ++ks) {
      bf16x8 af[4], bfr[2];
#pragma unroll
      for (int mi = 0; mi < 4; ++mi) {
        int Ra = wm * 64 + mi * 16 + l16;
        af[mi] = *(const bf16x8*)&As[p * 8192 + Ra * 64 + (((ks * 4 + quad) ^ (Ra & 7))) * 8];
      }
#pragma unroll
      for (int ni = 0; ni < 2; ++ni) {
        int Rb = wn * 32 + ni * 16 + l16;
        bfr[ni] = *(const bf16x8*)&Bs[p * 4096 + Rb * 64 + (((ks * 4 + quad) ^ (Rb & 7))) * 8];
      }
#pragma unroll
      for (int mi = 0; mi < 4; ++mi)
#pragma unroll
        for (int ni = 0; ni < 2; ++ni)
          acc[mi][ni] = mfma16(af[mi], bfr[ni], acc[mi][ni]);
    }
  };

  stage(0, 0);
  stage(1, 64);
  int cur = 0;
  for (int kt = 0; kt < 22; ++kt) {
    asm volatile("s_waitcnt vmcnt(6)" ::: "memory");
    __builtin_amdgcn_s_barrier();
    __builtin_amdgcn_sched_barrier(0);
    int nxt2 = cur + 2; if (nxt2 >= 3) nxt2 -= 3;
    stage(nxt2, (kt + 2) * 64);
    compute(cur);
    asm volatile("s_waitcnt lgkmcnt(0)" ::: "memory");
    __builtin_amdgcn_s_barrier();
    cur = (cur == 2) ? 0 : cur + 1;
  }
  asm volatile("s_waitcnt vmcnt(6)" ::: "memory");
  __builtin_amdgcn_s_barrier();
  __builtin_amdgcn_sched_barrier(0);
  compute(cur);
  cur = (cur == 2) ? 0 : cur + 1;
  asm volatile("s_waitcnt vmcnt(0)" ::: "memory");
  __builtin_amdgcn_s_barrier();
  __builtin_amdgcn_sched_barrier(0);
  compute(cur);

#pragma unroll
  for (int mi = 0; mi < 4; ++mi)
#pragma unroll
    for (int ni = 0; ni < 2; ++ni)
#pragma unroll
      for (int r = 0; r < 4; ++r) {
        int row = m0 + wm * 64 + mi * 16 + quad * 4 + r;
        int col = n0 + wn * 32 + ni * 16 + l16;
        out0[(size_t)row * CC + col] = acc[mi][ni][r] + bias0[col];
      }
}

// ---------------- split-K flash attention, LDS-staged K/V --------------------
// VERBATIM round-5 version (50.2us verified; rounds 6/7 variants regressed).
// grid 768: h=blk&7 (XCD pin), ks=(blk>>3)%3, q0=((blk>>3)/3)*64.
// Staging via global_load_lds (linear LDS dest + pre-swizzled source, G21).
// Counted waits: vmcnt(6) releases QK^T as soon as K lands; the 24KB V staging
// latency hides under QK^T+rel+softmax; vmcnt(0) only before PV. Raw
// s_barriers (A: protect prev-tile reads, B: K ready, C: V ready).
// exp2-domain softmax, T13 defer-max, T5 setprio.
__global__ __launch_bounds__(256, 3) void attn_split(
    const u16* __restrict__ qw, const u16* __restrict__ Kw,
    const u16* __restrict__ vT, const u16* __restrict__ WrT,
    const float* __restrict__ dW, const unsigned char* __restrict__ cidx_g,
    u16* __restrict__ o_part, float* __restrict__ m_part,
    float* __restrict__ l_part) {
  const int blk = blockIdx.x;
  const int h = blk & 7;
  const int g = blk >> 3;
  const int ks = g % 3;
  const int q0 = (g / 3) * 64;
  const int t = threadIdx.x;
  const int lane = t & 63, w = t >> 6;
  const int l16 = lane & 15, quad = lane >> 4;

  __shared__ u16 KsL[64 * 64];         //  8192 B
  __shared__ u16 VsL[192 * 64];        // 24576 B
  __shared__ float2 UW[64][17];        //  8704 B
  __shared__ unsigned char cidx[TT];   //  2048 B
  __shared__ u16 Pl[4][16 * 72];       //  9216 B (u_raw scratch pre-loop)

  *(uint2*)&cidx[t * 8] = *(const uint2*)&cidx_g[t * 8];

  const int qloc = w * 16 + l16;
  const int q_abs = q0 + qloc;
  const u16* qp = qw + ((size_t)h * TT + q_abs) * 64 + quad * 8;
  const bf16x8 aq0 = *(const bf16x8*)qp;
  const bf16x8 aq1 = *(const bf16x8*)(qp + 32);

  // ---- UW build: u[q][i] = qw[q].WrT_h[i] + dW[h][i]; suffix sums ----
  {
    const u16* wrt = WrT + h * 32 * 64;
    bf16x8 wb00 = *(const bf16x8*)&wrt[l16 * 64 + quad * 8];
    bf16x8 wb01 = *(const bf16x8*)&wrt[l16 * 64 + 32 + quad * 8];
    bf16x8 wb10 = *(const bf16x8*)&wrt[(16 + l16) * 64 + quad * 8];
    bf16x8 wb11 = *(const bf16x8*)&wrt[(16 + l16) * 64 + 32 + quad * 8];
    fx4 u0 = {}, u1 = {};
    u0 = mfma16(aq0, wb00, u0); u0 = mfma16(aq1, wb01, u0);
    u1 = mfma16(aq0, wb10, u1); u1 = mfma16(aq1, wb11, u1);
    float dw0 = dW[h * 32 + l16], dw1 = dW[h * 32 + 16 + l16];
    float* u_raw = (float*)&Pl[0][0];   // [64][33]
#pragma unroll
    for (int r = 0; r < 4; ++r) {
      int qrow = w * 16 + quad * 4 + r;
      u_raw[qrow * 33 + l16] = u0[r] + dw0;
      u_raw[qrow * 33 + 16 + l16] = u1[r] + dw1;
    }
    __syncthreads();
    if (t < 64) {
      float su = 0.f, sw = 0.f;
      float Uv[16], Wv[16];
#pragma unroll
      for (int c = 15; c >= 0; --c) {
        su += u_raw[t * 33 + c]; Uv[c] = su;
        sw += u_raw[t * 33 + 16 + c]; Wv[c] = sw;
      }
#pragma unroll
      for (int c = 0; c < 16; ++c) UW[t][c] = make_float2(Uv[c], Wv[c]);
    }
  }
  __syncthreads();  // UW ready; u_raw scratch dead -> Pl reusable

  float m_s = -3.0e38f, l_s = 0.0f;
  fx4 o[12] = {};
  const u16* kbase = Kw + (size_t)h * TT * 64;
  const u16* vbase = vT + (size_t)h * VV * TT;
  const int jtab[4] = {0, 704, 1408, 2048};
  const int jbeg = jtab[ks], jfin = jtab[ks + 1];

  for (int j0 = jbeg; j0 < jfin; j0 += 64) {
    // (A) all waves done reading prev tile's KsL/VsL (PV precedes this)
    __builtin_amdgcn_s_barrier();
    // ---- async staging: K first (2 chunks/thr), then V (6 chunks/thr) ------
#pragma unroll
    for (int i = 0; i < 2; ++i) {
      int chunk = i * 256 + t;
      int j = chunk >> 3, c = (chunk & 7) ^ (j & 7);
      gl_lds16(&kbase[(size_t)(j0 + j) * 64 + c * 8],
               &KsL[(size_t)(i * 256 + w * 64) * 8]);
    }
#pragma unroll
    for (int i = 0; i < 6; ++i) {
      int chunk = i * 256 + t;
      int v = chunk >> 3, c = (chunk & 7) ^ (v & 7);
      gl_lds16(&vbase[(size_t)v * TT + j0 + c * 8],
               &VsL[(size_t)(i * 256 + w * 64) * 8]);
    }
    // ---- rel-term prep while loads are in flight ----
    const int dbase = j0 + quad * 4 - q_abs;
    int cc[16];
#pragma unroll
    for (int jt = 0; jt < 4; ++jt)
#pragma unroll
      for (int r = 0; r < 4; ++r) {
        int d = dbase + jt * 16 + r;
        cc[jt * 4 + r] = cidx[d < 0 ? -d : d];
      }
    float2 uwv[16];
#pragma unroll
    for (int i = 0; i < 16; ++i) uwv[i] = UW[qloc][cc[i]];
    // (B) our K chunks landed (oldest 2 of 8 outstanding); barrier -> all K in
    asm volatile("s_waitcnt vmcnt(6)" ::: "memory");
    __builtin_amdgcn_s_barrier();
    __builtin_amdgcn_sched_barrier(0);
    // ---- K fragments from LDS, S^T = K.Q^T ----
    bf16x8 kf[8];
#pragma unroll
    for (int jt = 0; jt < 4; ++jt) {
      int j = jt * 16 + l16;
      kf[jt * 2]     = *(const bf16x8*)&KsL[j * 64 + ((quad) ^ (j & 7)) * 8];
      kf[jt * 2 + 1] = *(const bf16x8*)&KsL[j * 64 + ((quad + 4) ^ (j & 7)) * 8];
    }
    fx4 s[4];
    __builtin_amdgcn_s_setprio(1);
#pragma unroll
    for (int jt = 0; jt < 4; ++jt) {
      fx4 z = {0.f, 0.f, 0.f, 0.f};
      z = mfma16(kf[jt * 2], aq0, z);
      s[jt] = mfma16(kf[jt * 2 + 1], aq1, z);
    }
    __builtin_amdgcn_s_setprio(0);
#pragma unroll
    for (int jt = 0; jt < 4; ++jt)
#pragma unroll
      for (int r = 0; r < 4; ++r) {
        int d = dbase + jt * 16 + r;
        float2 z = uwv[jt * 4 + r];
        s[jt][r] += z.x + (d > 0 ? z.y : (d < 0 ? -z.y : 0.0f));
      }
    // ---- per-lane online softmax (exp2 domain) + cross-quad reduction ----
    float mx = s[0][0];
#pragma unroll
    for (int jt = 0; jt < 4; ++jt)
#pragma unroll
      for (int r = 0; r < 4; ++r) mx = fmaxf(mx, s[jt][r]);
    mx = fmaxf(mx, __shfl_xor(mx, 16, 64));
    mx = fmaxf(mx, __shfl_xor(mx, 32, 64));
    if (!__all(mx - m_s <= 8.0f)) {   // T13: rescale only on real max growth
      float mnew = fmaxf(m_s, mx);
      float alpha = exp2f(m_s - mnew);
      float a4[4];
#pragma unroll
      for (int r = 0; r < 4; ++r) a4[r] = __shfl(alpha, quad * 4 + r, 16);
#pragma unroll
      for (int vt = 0; vt < 12; ++vt)
#pragma unroll
        for (int r = 0; r < 4; ++r) o[vt][r] *= a4[r];
      l_s *= alpha;
      m_s = mnew;
    }
    float p16[16];
    float ps = 0.0f;
#pragma unroll
    for (int jt = 0; jt < 4; ++jt)
#pragma unroll
      for (int r = 0; r < 4; ++r) {
        float p = exp2f(s[jt][r] - m_s);
        p16[jt * 4 + r] = p;
        ps += p;
      }
    ps += __shfl_xor(ps, 16, 64);
    ps += __shfl_xor(ps, 32, 64);
    l_s += ps;
    // ---- P -> LDS (wave-private) -> A-operand ----
#pragma unroll
    for (int jt = 0; jt < 4; ++jt) {
      union { u16 h4[4]; uint2 v; } pk;
#pragma unroll
      for (int r = 0; r < 4; ++r) pk.h4[r] = f2bf(p16[jt * 4 + r]);
      *(uint2*)&Pl[w][l16 * 72 + jt * 16 + quad * 4] = pk.v;
    }
    asm volatile("s_waitcnt lgkmcnt(0)" ::: "memory");
    bf16x8 pf0 = *(const bf16x8*)&Pl[w][l16 * 72 + quad * 8];
    bf16x8 pf1 = *(const bf16x8*)&Pl[w][l16 * 72 + 32 + quad * 8];
    // (C) all V chunks landed everywhere; latency hidden under the above
    asm volatile("s_waitcnt vmcnt(0)" ::: "memory");
    __builtin_amdgcn_s_barrier();
    __builtin_amdgcn_sched_barrier(0);
    // ---- PV from LDS V tile ----
    __builtin_amdgcn_s_setprio(1);
#pragma unroll
    for (int vt = 0; vt < 12; ++vt) {
      int v = vt * 16 + l16;
      bf16x8 bv = *(const bf16x8*)&VsL[v * 64 + ((quad) ^ (v & 7)) * 8];
      o[vt] = mfma16(pf0, bv, o[vt]);
    }
#pragma unroll
    for (int vt = 0; vt < 12; ++vt) {
      int v = vt * 16 + l16;
      bf16x8 bv = *(const bf16x8*)&VsL[v * 64 + ((quad + 4) ^ (v & 7)) * 8];
      o[vt] = mfma16(pf1, bv, o[vt]);
    }
    __builtin_amdgcn_s_setprio(0);
  }

#pragma unroll
  for (int r = 0; r < 4; ++r) {
    int row = q0 + w * 16 + quad * 4 + r;
    size_t base = ((size_t)(ks * HH + h) * TT + row) * VV;
#pragma unroll
    for (int vt = 0; vt < 12; ++vt) o_part[base + vt * 16 + l16] = f2bf(o[vt][r]);
  }
  if (quad == 0) {
    m_part[(size_t)(ks * HH + h) * TT + q_abs] = m_s;
    l_part[(size_t)(ks * HH + h) * TT + q_abs] = l_s;
  }
}

// ---------------- combine split-K partials -> bf16 aout ----------------------
// m_part is in log2 domain -> exp2f weights.
__global__ __launch_bounds__(256) void attn_combine(
    const u16* __restrict__ o_part, const float* __restrict__ m_part,
    const float* __restrict__ l_part, u16* __restrict__ aout) {
  const int h = blockIdx.y;
  const int row = blockIdx.x * 16 + (threadIdx.x >> 4);
  const int c0 = (threadIdx.x & 15) * 12;

  float m[SPLITS], M = -3.0e38f;
#pragma unroll
  for (int s = 0; s < SPLITS; ++s) {
    m[s] = m_part[(size_t)(s * HH + h) * TT + row];
    M = fmaxf(M, m[s]);
  }
  float lsum = 0.0f, wgt[SPLITS];
#pragma unroll
  for (int s = 0; s < SPLITS; ++s) {
    wgt[s] = exp2f(m[s] - M);
    lsum += wgt[s] * l_part[(size_t)(s * HH + h) * TT + row];
  }
  float o[12];
#pragma unroll
  for (int j = 0; j < 12; ++j) o[j] = 0.0f;
#pragma unroll
  for (int s = 0; s < SPLITS; ++s) {
    const u16* op = o_part + ((size_t)(s * HH + h) * TT + row) * VV + c0;
    float wgts = wgt[s];
    uint2 u0 = *(const uint2*)&op[0];
    uint2 u1 = *(const uint2*)&op[4];
    uint2 u2 = *(const uint2*)&op[8];
    u32 uu[6] = {u0.x, u0.y, u1.x, u1.y, u2.x, u2.y};
#pragma unroll
    for (int j = 0; j < 6; ++j) {
      o[j * 2 + 0] = fmaf(wgts, bf2f((u16)(uu[j] & 0xFFFF)), o[j * 2 + 0]);
      o[j * 2 + 1] = fmaf(wgts, bf2f((u16)(uu[j] >> 16)), o[j * 2 + 1]);
    }
  }
  float inv = 1.0f / lsum;
  union { u16 hx[12]; uint2 v2[3]; } pk;
#pragma unroll
  for (int j = 0; j < 12; ++j) pk.hx[j] = f2bf(o[j] * inv);
  u16* dst = aout + (size_t)row * CC + h * VV + c0;
  *(uint2*)&dst[0] = pk.v2[0];
  *(uint2*)&dst[4] = pk.v2[1];
  *(uint2*)&dst[8] = pk.v2[2];
}

extern "C" void kernel_launch(void* const* d_in, const int* in_sizes, int n_in,
                              void* d_out, int out_size, void* d_ws, size_t ws_size,
                              hipStream_t stream) {
  (void)in_sizes; (void)n_in; (void)out_size; (void)ws_size;
  const float* x   = (const float*)d_in[0];
  const float* Wq  = (const float*)d_in[1];
  const float* Wk  = (const float*)d_in[2];
  const float* Wv  = (const float*)d_in[3];
  const float* Wr  = (const float*)d_in[4];
  const float* rwb = (const float*)d_in[5];
  const float* rrb = (const float*)d_in[6];
  const float* Wo  = (const float*)d_in[7];
  const float* bo  = (const float*)d_in[8];

  char* ws = (char*)d_ws;
  size_t off = 0;
  auto alloc = [&](size_t bytes) -> void* {
    void* p = ws + off;
    off += (bytes + 255) & ~(size_t)255;
    return p;
  };
  u16* WqT  = (u16*)alloc((size_t)512 * 1536 * 2);
  u16* WkT  = (u16*)alloc((size_t)512 * 1536 * 2);
  u16* WvT  = (u16*)alloc((size_t)1536 * 1536 * 2);
  u16* WoT  = (u16*)alloc((size_t)1536 * 1536 * 2);
  u16* xbf  = (u16*)alloc((size_t)TT * CC * 2);
  u16* qw   = (u16*)alloc((size_t)HH * TT * 64 * 2);
  u16* Kws  = (u16*)alloc((size_t)HH * TT * 64 * 2);
  u16* vTw  = (u16*)alloc((size_t)HH * VV * TT * 2);
  u16* aout = (u16*)alloc((size_t)TT * CC * 2);
  unsigned char* cidx_g = (unsigned char*)alloc(TT);
  u16* WrT      = (u16*)alloc((size_t)HH * 32 * 64 * 2);
  float* dW     = (float*)alloc((size_t)HH * 32 * 4);
  u16* o_part   = (u16*)alloc((size_t)SPLITS * HH * TT * VV * 2);
  float* m_part = (float*)alloc((size_t)SPLITS * HH * TT * 4);
  float* l_part = (float*)alloc((size_t)SPLITS * HH * TT * 4);

  prep_kernel<<<dim3(24, 24, 6), 256, 0, stream>>>(
      Wq, Wk, Wv, Wo, x, Wr, rwb, rrb,
      WqT, WkT, WvT, WoT, xbf, cidx_g, WrT, dW);
  gemm_qkv<<<dim3(40, 16), 256, 0, stream>>>(xbf, WqT, WkT, WvT,
                                             qw, Kws, vTw, rwb);
  attn_split<<<dim3(768), 256, 0, stream>>>(qw, Kws, vTw, WrT, dW, cidx_g,
                                            o_part, m_part, l_part);
  attn_combine<<<dim3(128, 8), 256, 0, stream>>>(o_part, m_part, l_part, aout);
  gemm_out<<<dim3(12 * 2, 16), 256, 0, stream>>>(aout, WoT, (float*)d_out, bo);
}

// Round 9
// 201.125 us; speedup vs baseline: 1.1054x; 1.1054x over previous
//
#include <hip/hip_runtime.h>
#include <hip/hip_bf16.h>

typedef unsigned short u16;
typedef unsigned int u32;
typedef __bf16 bf16_t;
typedef bf16_t bf16x8 __attribute__((ext_vector_type(8)));
typedef float fx4 __attribute__((ext_vector_type(4)));

#define TT 2048
#define HH 8
#define KK 64
#define VV 192
#define CC 1536
#define SPLITS 3
#define LOG2E 1.4426950408889634f

__device__ __forceinline__ float bf2f(u16 b) {
  union { u32 u; float f; } v; v.u = ((u32)b) << 16; return v.f;
}
__device__ __forceinline__ u16 f2bf(float f) {
  union { float f; u32 u; } v; v.f = f;
  return (u16)((v.u + 0x7FFFu + ((v.u >> 16) & 1u)) >> 16);
}
// native RNE cast -- pairs fuse to v_cvt_pk_bf16_f32 (attn hot path only)
__device__ __forceinline__ u16 f2bf_n(float f) {
  union { bf16_t b; u16 u; } v; v.b = (bf16_t)f; return v.u;
}
__device__ __forceinline__ fx4 mfma16(bf16x8 a, bf16x8 b, fx4 c) {
  return __builtin_amdgcn_mfma_f32_16x16x32_bf16(a, b, c, 0, 0, 0);
}
// async global->LDS, 16B/lane; LDS dest = wave-uniform base, lane*16 implicit
__device__ __forceinline__ void gl_lds16(const u16* g, u16* l) {
  __builtin_amdgcn_global_load_lds(
      (const __attribute__((address_space(1))) u32*)g,
      (__attribute__((address_space(3))) u32*)l, 16, 0, 0);
}

// ------ prep: weight transposes + cidx/WrT/dW tables + x conversion ----------
// z=0..3: weight transposes; z=4 (y==0, x=0/1/2 split): tables; z=5: x->bf16.
__global__ __launch_bounds__(256) void prep_kernel(
    const float* __restrict__ Wq, const float* __restrict__ Wk,
    const float* __restrict__ Wv, const float* __restrict__ Wo,
    const float* __restrict__ x, const float* __restrict__ Wr,
    const float* __restrict__ rwb, const float* __restrict__ rrb,
    u16* __restrict__ WqT, u16* __restrict__ WkT,
    u16* __restrict__ WvT, u16* __restrict__ WoT,
    u16* __restrict__ xbf, unsigned char* __restrict__ cidx_g,
    u16* __restrict__ WrT, float* __restrict__ dW) {
  const int z = blockIdx.z;
  const int t = threadIdx.x;
  if (z == 4) {
    if (blockIdx.y != 0 || blockIdx.x >= 3) return;
    if (blockIdx.x == 0) {
      // cidx: borzoi center-width category per |distance|
      float pr = expf(logf((float)(TT + 1)) / 16.0f);
      float cw[16];
      float wv = pr;
      for (int i = 0; i < 16; ++i) { cw[i] = wv - 1.0f; wv *= pr; }
      for (int idx = t; idx < TT; idx += 256) {
        int c = 15;
        for (int i = 14; i >= 0; --i)
          if (cw[i] > (float)idx) c = i;
        cidx_g[idx] = (unsigned char)c;
      }
    } else if (blockIdx.x == 1) {
      // WrT[h][i][k] bf16 from Wr f32 [32][512]
      for (int idx = t; idx < 8 * 32 * 64; idx += 256) {
        int hh = idx >> 11, rem = idx & 2047;
        int i = rem >> 6, k = rem & 63;
        WrT[idx] = f2bf(Wr[i * 512 + hh * 64 + k]);
      }
    } else {
      // dW[h*32+i] = sum_k (rrb - rwb)[h*64+k] * Wr[i][h*64+k]  (log2e-scaled)
      int hh = t >> 5, i = t & 31;
      float s = 0.0f;
      for (int k = 0; k < 64; ++k)
        s += (rrb[hh * 64 + k] - rwb[hh * 64 + k]) * Wr[i * 512 + hh * 64 + k];
      dW[t] = s * LOG2E;
    }
    return;
  }
  if (z == 5) {
    const size_t ngroups = (size_t)TT * CC / 8;
    int bid = blockIdx.y * 24 + blockIdx.x;  // 0..575
    for (size_t g = (size_t)bid * 256 + t; g < ngroups; g += (size_t)576 * 256) {
      size_t i = g * 8;
      float4 f0 = *(const float4*)&x[i];
      float4 f1 = *(const float4*)&x[i + 4];
      union { u16 h[8]; uint4 v; } pk;
      pk.h[0] = f2bf(f0.x); pk.h[1] = f2bf(f0.y);
      pk.h[2] = f2bf(f0.z); pk.h[3] = f2bf(f0.w);
      pk.h[4] = f2bf(f1.x); pk.h[5] = f2bf(f1.y);
      pk.h[6] = f2bf(f1.z); pk.h[7] = f2bf(f1.w);
      *(uint4*)&xbf[i] = pk.v;
    }
    return;
  }
  if (z < 2 && blockIdx.x >= 8) return;
  const float* in = (z == 0) ? Wq : (z == 1) ? Wk : (z == 2) ? Wv : Wo;
  u16* out = (z == 0) ? WqT : (z == 1) ? WkT : (z == 2) ? WvT : WoT;
  const int in_rs = (z < 2) ? 512 : 1536;
  const int out_rs = 1536;

  __shared__ u16 tile[64][68];
  const int c0 = blockIdx.x * 64, r0 = blockIdx.y * 64;
#pragma unroll
  for (int i = 0; i < 4; ++i) {
    int idx = i * 256 + t;
    int r = idx >> 4, ch = idx & 15;
    float4 fv = *(const float4*)&in[(size_t)(r0 + r) * in_rs + c0 + ch * 4];
    tile[r][ch * 4 + 0] = f2bf(fv.x);
    tile[r][ch * 4 + 1] = f2bf(fv.y);
    tile[r][ch * 4 + 2] = f2bf(fv.z);
    tile[r][ch * 4 + 3] = f2bf(fv.w);
  }
  __syncthreads();
#pragma unroll
  for (int i = 0; i < 4; ++i) {
    int idx = i * 256 + t;
    int r = idx >> 4, ch = idx & 15;
    u16 a0 = tile[ch * 4 + 0][r], a1 = tile[ch * 4 + 1][r];
    u16 a2 = tile[ch * 4 + 2][r], a3 = tile[ch * 4 + 3][r];
    uint2 d;
    d.x = (u32)a0 | ((u32)a1 << 16);
    d.y = (u32)a2 | ((u32)a3 << 16);
    *(uint2*)&out[(size_t)(c0 + r) * out_rs + r0 + ch * 4] = d;
  }
}

// ---------------- unified QKV projection GEMM (bf16 A) -----------------------
// ROUND-5 VERBATIM (verified best; round-8 3-buffer variant regressed).
// BM=128 BN=64 BK=64, double-buffered LDS + 2-phase pipeline:
// STAGE(next) issued BEFORE compute(cur); one vmcnt(0)+s_barrier per k-step.
// Both-sides XOR swizzle (chunk^row&7) -> conflict-free ds_read_b128.
// grid (40,16): cb<8 -> Q (scale+bias, log2e), cb<16 -> K, else V (vT write).
__global__ __launch_bounds__(256) void gemm_qkv(
    const u16* __restrict__ xbf, const u16* __restrict__ WqT,
    const u16* __restrict__ WkT, const u16* __restrict__ WvT,
    u16* __restrict__ qw, u16* __restrict__ Kws, u16* __restrict__ vTw,
    const float* __restrict__ rwb) {
  __shared__ u16 As[2][128 * 64];  // 2 x 16 KB
  __shared__ u16 Bs[2][64 * 64];   // 2 x  8 KB
  const int cb = blockIdx.x;
  const u16* BT = (cb < 8) ? WqT : (cb < 16) ? WkT : WvT;
  const int n0 = ((cb < 8) ? cb : (cb < 16) ? cb - 8 : cb - 16) * 64;
  const int t = threadIdx.x;
  const int lane = t & 63, wid = t >> 6;
  const int l16 = lane & 15, quad = lane >> 4;
  const int wm = wid >> 1, wn = wid & 1;
  const int m0 = blockIdx.y * 128;
  const int wbase = wid * 512;  // wave-uniform LDS chunk base (u16 idx)

  auto stage = [&](int p, int k0) {
#pragma unroll
    for (int i = 0; i < 4; ++i) {
      int chunk = i * 256 + t;
      int r = chunk >> 3, c = (chunk & 7) ^ (r & 7);
      gl_lds16(&xbf[(size_t)(m0 + r) * CC + k0 + c * 8], &As[p][i * 2048 + wbase]);
    }
#pragma unroll
    for (int i = 0; i < 2; ++i) {
      int chunk = i * 256 + t;
      int r = chunk >> 3, c = (chunk & 7) ^ (r & 7);
      gl_lds16(&BT[(size_t)(n0 + r) * CC + k0 + c * 8], &Bs[p][i * 2048 + wbase]);
    }
  };

  fx4 acc[4][2] = {};
  stage(0, 0);
  asm volatile("s_waitcnt vmcnt(0)" ::: "memory");
  __builtin_amdgcn_s_barrier();
  int p = 0;
  for (int kt = 0; kt < 24; ++kt) {
    if (kt != 23) stage(p ^ 1, (kt + 1) * 64);
#pragma unroll
    for (int ks = 0; ks < 2; ++ks) {
      bf16x8 af[4], bfr[2];
#pragma unroll
      for (int mi = 0; mi < 4; ++mi) {
        int Ra = wm * 64 + mi * 16 + l16;
        af[mi] = *(const bf16x8*)&As[p][Ra * 64 + (((ks * 4 + quad) ^ (Ra & 7))) * 8];
      }
#pragma unroll
      for (int ni = 0; ni < 2; ++ni) {
        int Rb = wn * 32 + ni * 16 + l16;
        bfr[ni] = *(const bf16x8*)&Bs[p][Rb * 64 + (((ks * 4 + quad) ^ (Rb & 7))) * 8];
      }
#pragma unroll
      for (int mi = 0; mi < 4; ++mi)
#pragma unroll
        for (int ni = 0; ni < 2; ++ni)
          acc[mi][ni] = mfma16(af[mi], bfr[ni], acc[mi][ni]);
    }
    asm volatile("s_waitcnt vmcnt(0)" ::: "memory");
    __builtin_amdgcn_s_barrier();
    p ^= 1;
  }

#pragma unroll
  for (int mi = 0; mi < 4; ++mi)
#pragma unroll
    for (int ni = 0; ni < 2; ++ni) {
      int col = n0 + wn * 32 + ni * 16 + l16;
      int row0 = m0 + wm * 64 + mi * 16 + quad * 4;
      if (cb < 16) {
        int h = col >> 6, kx = col & 63;
#pragma unroll
        for (int r = 0; r < 4; ++r) {
          float v = acc[mi][ni][r];
          size_t o = ((size_t)h * TT + row0 + r) * 64 + kx;
          if (cb < 8) qw[o] = f2bf((v * 0.125f + rwb[col]) * LOG2E);
          else Kws[o] = f2bf(v);
        }
      } else {
        // direct transposed V write: vTw[h][vv][t], 4 consecutive t per lane
        // col is ALREADY rebased to [0,1536) via n0 = (cb-16)*64.
        int h = col / 192, vv = col - h * 192;
        union { u16 h4[4]; uint2 v2; } pk;
#pragma unroll
        for (int r = 0; r < 4; ++r) pk.h4[r] = f2bf(acc[mi][ni][r]);
        *(uint2*)&vTw[(size_t)h * VV * TT + (size_t)vv * TT + row0] = pk.v2;
      }
    }
}

// ---------------- out-projection GEMM: FLOAT out = A@WoT^T + bias ------------
// ROUND-5 VERBATIM. Same BM=128 BN=64 BK=64 dbuf pipeline. grid (24,16).
__global__ __launch_bounds__(256) void gemm_out(
    const u16* __restrict__ A, const u16* __restrict__ BT,
    float* __restrict__ out0, const float* __restrict__ bias0) {
  __shared__ u16 As[2][128 * 64];
  __shared__ u16 Bs[2][64 * 64];
  const int t = threadIdx.x;
  const int lane = t & 63, wid = t >> 6;
  const int l16 = lane & 15, quad = lane >> 4;
  const int wm = wid >> 1, wn = wid & 1;
  const int m0 = blockIdx.y * 128, n0 = blockIdx.x * 64;
  const int wbase = wid * 512;

  auto stage = [&](int p, int k0) {
#pragma unroll
    for (int i = 0; i < 4; ++i) {
      int chunk = i * 256 + t;
      int r = chunk >> 3, c = (chunk & 7) ^ (r & 7);
      gl_lds16(&A[(size_t)(m0 + r) * CC + k0 + c * 8], &As[p][i * 2048 + wbase]);
    }
#pragma unroll
    for (int i = 0; i < 2; ++i) {
      int chunk = i * 256 + t;
      int r = chunk >> 3, c = (chunk & 7) ^ (r & 7);
      gl_lds16(&BT[(size_t)(n0 + r) * CC + k0 + c * 8], &Bs[p][i * 2048 + wbase]);
    }
  };

  fx4 acc[4][2] = {};
  stage(0, 0);
  asm volatile("s_waitcnt vmcnt(0)" ::: "memory");
  __builtin_amdgcn_s_barrier();
  int p = 0;
  for (int kt = 0; kt < 24; ++kt) {
    if (kt != 23) stage(p ^ 1, (kt + 1) * 64);
#pragma unroll
    for (int ks = 0; ks < 2; ++ks) {
      bf16x8 af[4], bfr[2];
#pragma unroll
      for (int mi = 0; mi < 4; ++mi) {
        int Ra = wm * 64 + mi * 16 + l16;
        af[mi] = *(const bf16x8*)&As[p][Ra * 64 + (((ks * 4 + quad) ^ (Ra & 7))) * 8];
      }
#pragma unroll
      for (int ni = 0; ni < 2; ++ni) {
        int Rb = wn * 32 + ni * 16 + l16;
        bfr[ni] = *(const bf16x8*)&Bs[p][Rb * 64 + (((ks * 4 + quad) ^ (Rb & 7))) * 8];
      }
#pragma unroll
      for (int mi = 0; mi < 4; ++mi)
#pragma unroll
        for (int ni = 0; ni < 2; ++ni)
          acc[mi][ni] = mfma16(af[mi], bfr[ni], acc[mi][ni]);
    }
    asm volatile("s_waitcnt vmcnt(0)" ::: "memory");
    __builtin_amdgcn_s_barrier();
    p ^= 1;
  }
#pragma unroll
  for (int mi = 0; mi < 4; ++mi)
#pragma unroll
    for (int ni = 0; ni < 2; ++ni)
#pragma unroll
      for (int r = 0; r < 4; ++r) {
        int row = m0 + wm * 64 + mi * 16 + quad * 4 + r;
        int col = n0 + wn * 32 + ni * 16 + l16;
        out0[(size_t)row * CC + col] = acc[mi][ni][r] + bias0[col];
      }
}

// ---------------- split-K flash attention, LDS-staged K/V --------------------
// ROUND-5 structure (50.2us verified) + native cvt_pk bf16 pack in the
// P->LDS path and o_part epilogue (f2bf_n: 64 -> ~8 VALU ops per tile).
// grid 768: h=blk&7 (XCD pin), ks=(blk>>3)%3, q0=((blk>>3)/3)*64.
// Counted waits: vmcnt(6) releases QK^T as soon as K lands; V latency hides
// under QK^T+rel+softmax; vmcnt(0) only before PV. Raw s_barriers (A/B/C).
// exp2-domain softmax, T13 defer-max, T5 setprio.
__global__ __launch_bounds__(256, 3) void attn_split(
    const u16* __restrict__ qw, const u16* __restrict__ Kw,
    const u16* __restrict__ vT, const u16* __restrict__ WrT,
    const float* __restrict__ dW, const unsigned char* __restrict__ cidx_g,
    u16* __restrict__ o_part, float* __restrict__ m_part,
    float* __restrict__ l_part) {
  const int blk = blockIdx.x;
  const int h = blk & 7;
  const int g = blk >> 3;
  const int ks = g % 3;
  const int q0 = (g / 3) * 64;
  const int t = threadIdx.x;
  const int lane = t & 63, w = t >> 6;
  const int l16 = lane & 15, quad = lane >> 4;

  __shared__ u16 KsL[64 * 64];         //  8192 B
  __shared__ u16 VsL[192 * 64];        // 24576 B
  __shared__ float2 UW[64][17];        //  8704 B
  __shared__ unsigned char cidx[TT];   //  2048 B
  __shared__ u16 Pl[4][16 * 72];       //  9216 B (u_raw scratch pre-loop)

  *(uint2*)&cidx[t * 8] = *(const uint2*)&cidx_g[t * 8];

  const int qloc = w * 16 + l16;
  const int q_abs = q0 + qloc;
  const u16* qp = qw + ((size_t)h * TT + q_abs) * 64 + quad * 8;
  const bf16x8 aq0 = *(const bf16x8*)qp;
  const bf16x8 aq1 = *(const bf16x8*)(qp + 32);

  // ---- UW build: u[q][i] = qw[q].WrT_h[i] + dW[h][i]; suffix sums ----
  {
    const u16* wrt = WrT + h * 32 * 64;
    bf16x8 wb00 = *(const bf16x8*)&wrt[l16 * 64 + quad * 8];
    bf16x8 wb01 = *(const bf16x8*)&wrt[l16 * 64 + 32 + quad * 8];
    bf16x8 wb10 = *(const bf16x8*)&wrt[(16 + l16) * 64 + quad * 8];
    bf16x8 wb11 = *(const bf16x8*)&wrt[(16 + l16) * 64 + 32 + quad * 8];
    fx4 u0 = {}, u1 = {};
    u0 = mfma16(aq0, wb00, u0); u0 = mfma16(aq1, wb01, u0);
    u1 = mfma16(aq0, wb10, u1); u1 = mfma16(aq1, wb11, u1);
    float dw0 = dW[h * 32 + l16], dw1 = dW[h * 32 + 16 + l16];
    float* u_raw = (float*)&Pl[0][0];   // [64][33]
#pragma unroll
    for (int r = 0; r < 4; ++r) {
      int qrow = w * 16 + quad * 4 + r;
      u_raw[qrow * 33 + l16] = u0[r] + dw0;
      u_raw[qrow * 33 + 16 + l16] = u1[r] + dw1;
    }
    __syncthreads();
    if (t < 64) {
      float su = 0.f, sw = 0.f;
      float Uv[16], Wv[16];
#pragma unroll
      for (int c = 15; c >= 0; --c) {
        su += u_raw[t * 33 + c]; Uv[c] = su;
        sw += u_raw[t * 33 + 16 + c]; Wv[c] = sw;
      }
#pragma unroll
      for (int c = 0; c < 16; ++c) UW[t][c] = make_float2(Uv[c], Wv[c]);
    }
  }
  __syncthreads();  // UW ready; u_raw scratch dead -> Pl reusable

  float m_s = -3.0e38f, l_s = 0.0f;
  fx4 o[12] = {};
  const u16* kbase = Kw + (size_t)h * TT * 64;
  const u16* vbase = vT + (size_t)h * VV * TT;
  const int jtab[4] = {0, 704, 1408, 2048};
  const int jbeg = jtab[ks], jfin = jtab[ks + 1];

  for (int j0 = jbeg; j0 < jfin; j0 += 64) {
    // (A) all waves done reading prev tile's KsL/VsL (PV precedes this)
    __builtin_amdgcn_s_barrier();
    // ---- async staging: K first (2 chunks/thr), then V (6 chunks/thr) ------
#pragma unroll
    for (int i = 0; i < 2; ++i) {
      int chunk = i * 256 + t;
      int j = chunk >> 3, c = (chunk & 7) ^ (j & 7);
      gl_lds16(&kbase[(size_t)(j0 + j) * 64 + c * 8],
               &KsL[(size_t)(i * 256 + w * 64) * 8]);
    }
#pragma unroll
    for (int i = 0; i < 6; ++i) {
      int chunk = i * 256 + t;
      int v = chunk >> 3, c = (chunk & 7) ^ (v & 7);
      gl_lds16(&vbase[(size_t)v * TT + j0 + c * 8],
               &VsL[(size_t)(i * 256 + w * 64) * 8]);
    }
    // ---- rel-term prep while loads are in flight ----
    const int dbase = j0 + quad * 4 - q_abs;
    int cc[16];
#pragma unroll
    for (int jt = 0; jt < 4; ++jt)
#pragma unroll
      for (int r = 0; r < 4; ++r) {
        int d = dbase + jt * 16 + r;
        cc[jt * 4 + r] = cidx[d < 0 ? -d : d];
      }
    float2 uwv[16];
#pragma unroll
    for (int i = 0; i < 16; ++i) uwv[i] = UW[qloc][cc[i]];
    // (B) our K chunks landed (oldest 2 of 8 outstanding); barrier -> all K in
    asm volatile("s_waitcnt vmcnt(6)" ::: "memory");
    __builtin_amdgcn_s_barrier();
    __builtin_amdgcn_sched_barrier(0);
    // ---- K fragments from LDS, S^T = K.Q^T ----
    bf16x8 kf[8];
#pragma unroll
    for (int jt = 0; jt < 4; ++jt) {
      int j = jt * 16 + l16;
      kf[jt * 2]     = *(const bf16x8*)&KsL[j * 64 + ((quad) ^ (j & 7)) * 8];
      kf[jt * 2 + 1] = *(const bf16x8*)&KsL[j * 64 + ((quad + 4) ^ (j & 7)) * 8];
    }
    fx4 s[4];
    __builtin_amdgcn_s_setprio(1);
#pragma unroll
    for (int jt = 0; jt < 4; ++jt) {
      fx4 z = {0.f, 0.f, 0.f, 0.f};
      z = mfma16(kf[jt * 2], aq0, z);
      s[jt] = mfma16(kf[jt * 2 + 1], aq1, z);
    }
    __builtin_amdgcn_s_setprio(0);
#pragma unroll
    for (int jt = 0; jt < 4; ++jt)
#pragma unroll
      for (int r = 0; r < 4; ++r) {
        int d = dbase + jt * 16 + r;
        float2 z = uwv[jt * 4 + r];
        s[jt][r] += z.x + (d > 0 ? z.y : (d < 0 ? -z.y : 0.0f));
      }
    // ---- per-lane online softmax (exp2 domain) + cross-quad reduction ----
    float mx = s[0][0];
#pragma unroll
    for (int jt = 0; jt < 4; ++jt)
#pragma unroll
      for (int r = 0; r < 4; ++r) mx = fmaxf(mx, s[jt][r]);
    mx = fmaxf(mx, __shfl_xor(mx, 16, 64));
    mx = fmaxf(mx, __shfl_xor(mx, 32, 64));
    if (!__all(mx - m_s <= 8.0f)) {   // T13: rescale only on real max growth
      float mnew = fmaxf(m_s, mx);
      float alpha = exp2f(m_s - mnew);
      float a4[4];
#pragma unroll
      for (int r = 0; r < 4; ++r) a4[r] = __shfl(alpha, quad * 4 + r, 16);
#pragma unroll
      for (int vt = 0; vt < 12; ++vt)
#pragma unroll
        for (int r = 0; r < 4; ++r) o[vt][r] *= a4[r];
      l_s *= alpha;
      m_s = mnew;
    }
    float p16[16];
    float ps = 0.0f;
#pragma unroll
    for (int jt = 0; jt < 4; ++jt)
#pragma unroll
      for (int r = 0; r < 4; ++r) {
        float p = exp2f(s[jt][r] - m_s);
        p16[jt * 4 + r] = p;
        ps += p;
      }
    ps += __shfl_xor(ps, 16, 64);
    ps += __shfl_xor(ps, 32, 64);
    l_s += ps;
    // ---- P -> LDS (wave-private) -> A-operand (native cvt_pk pack) ----
#pragma unroll
    for (int jt = 0; jt < 4; ++jt) {
      union { u16 h4[4]; uint2 v; } pk;
#pragma unroll
      for (int r = 0; r < 4; ++r) pk.h4[r] = f2bf_n(p16[jt * 4 + r]);
      *(uint2*)&Pl[w][l16 * 72 + jt * 16 + quad * 4] = pk.v;
    }
    asm volatile("s_waitcnt lgkmcnt(0)" ::: "memory");
    bf16x8 pf0 = *(const bf16x8*)&Pl[w][l16 * 72 + quad * 8];
    bf16x8 pf1 = *(const bf16x8*)&Pl[w][l16 * 72 + 32 + quad * 8];
    // (C) all V chunks landed everywhere; latency hidden under the above
    asm volatile("s_waitcnt vmcnt(0)" ::: "memory");
    __builtin_amdgcn_s_barrier();
    __builtin_amdgcn_sched_barrier(0);
    // ---- PV from LDS V tile ----
    __builtin_amdgcn_s_setprio(1);
#pragma unroll
    for (int vt = 0; vt < 12; ++vt) {
      int v = vt * 16 + l16;
      bf16x8 bv = *(const bf16x8*)&VsL[v * 64 + ((quad) ^ (v & 7)) * 8];
      o[vt] = mfma16(pf0, bv, o[vt]);
    }
#pragma unroll
    for (int vt = 0; vt < 12; ++vt) {
      int v = vt * 16 + l16;
      bf16x8 bv = *(const bf16x8*)&VsL[v * 64 + ((quad + 4) ^ (v & 7)) * 8];
      o[vt] = mfma16(pf1, bv, o[vt]);
    }
    __builtin_amdgcn_s_setprio(0);
  }

#pragma unroll
  for (int r = 0; r < 4; ++r) {
    int row = q0 + w * 16 + quad * 4 + r;
    size_t base = ((size_t)(ks * HH + h) * TT + row) * VV;
#pragma unroll
    for (int vt = 0; vt < 12; ++vt) o_part[base + vt * 16 + l16] = f2bf_n(o[vt][r]);
  }
  if (quad == 0) {
    m_part[(size_t)(ks * HH + h) * TT + q_abs] = m_s;
    l_part[(size_t)(ks * HH + h) * TT + q_abs] = l_s;
  }
}

// ---------------- combine split-K partials -> bf16 aout ----------------------
// m_part is in log2 domain -> exp2f weights.
__global__ __launch_bounds__(256) void attn_combine(
    const u16* __restrict__ o_part, const float* __restrict__ m_part,
    const float* __restrict__ l_part, u16* __restrict__ aout) {
  const int h = blockIdx.y;
  const int row = blockIdx.x * 16 + (threadIdx.x >> 4);
  const int c0 = (threadIdx.x & 15) * 12;

  float m[SPLITS], M = -3.0e38f;
#pragma unroll
  for (int s = 0; s < SPLITS; ++s) {
    m[s] = m_part[(size_t)(s * HH + h) * TT + row];
    M = fmaxf(M, m[s]);
  }
  float lsum = 0.0f, wgt[SPLITS];
#pragma unroll
  for (int s = 0; s < SPLITS; ++s) {
    wgt[s] = exp2f(m[s] - M);
    lsum += wgt[s] * l_part[(size_t)(s * HH + h) * TT + row];
  }
  float o[12];
#pragma unroll
  for (int j = 0; j < 12; ++j) o[j] = 0.0f;
#pragma unroll
  for (int s = 0; s < SPLITS; ++s) {
    const u16* op = o_part + ((size_t)(s * HH + h) * TT + row) * VV + c0;
    float wgts = wgt[s];
    uint2 u0 = *(const uint2*)&op[0];
    uint2 u1 = *(const uint2*)&op[4];
    uint2 u2 = *(const uint2*)&op[8];
    u32 uu[6] = {u0.x, u0.y, u1.x, u1.y, u2.x, u2.y};
#pragma unroll
    for (int j = 0; j < 6; ++j) {
      o[j * 2 + 0] = fmaf(wgts, bf2f((u16)(uu[j] & 0xFFFF)), o[j * 2 + 0]);
      o[j * 2 + 1] = fmaf(wgts, bf2f((u16)(uu[j] >> 16)), o[j * 2 + 1]);
    }
  }
  float inv = 1.0f / lsum;
  union { u16 hx[12]; uint2 v2[3]; } pk;
#pragma unroll
  for (int j = 0; j < 12; ++j) pk.hx[j] = f2bf(o[j] * inv);
  u16* dst = aout + (size_t)row * CC + h * VV + c0;
  *(uint2*)&dst[0] = pk.v2[0];
  *(uint2*)&dst[4] = pk.v2[1];
  *(uint2*)&dst[8] = pk.v2[2];
}

extern "C" void kernel_launch(void* const* d_in, const int* in_sizes, int n_in,
                              void* d_out, int out_size, void* d_ws, size_t ws_size,
                              hipStream_t stream) {
  (void)in_sizes; (void)n_in; (void)out_size; (void)ws_size;
  const float* x   = (const float*)d_in[0];
  const float* Wq  = (const float*)d_in[1];
  const float* Wk  = (const float*)d_in[2];
  const float* Wv  = (const float*)d_in[3];
  const float* Wr  = (const float*)d_in[4];
  const float* rwb = (const float*)d_in[5];
  const float* rrb = (const float*)d_in[6];
  const float* Wo  = (const float*)d_in[7];
  const float* bo  = (const float*)d_in[8];

  char* ws = (char*)d_ws;
  size_t off = 0;
  auto alloc = [&](size_t bytes) -> void* {
    void* p = ws + off;
    off += (bytes + 255) & ~(size_t)255;
    return p;
  };
  u16* WqT  = (u16*)alloc((size_t)512 * 1536 * 2);
  u16* WkT  = (u16*)alloc((size_t)512 * 1536 * 2);
  u16* WvT  = (u16*)alloc((size_t)1536 * 1536 * 2);
  u16* WoT  = (u16*)alloc((size_t)1536 * 1536 * 2);
  u16* xbf  = (u16*)alloc((size_t)TT * CC * 2);
  u16* qw   = (u16*)alloc((size_t)HH * TT * 64 * 2);
  u16* Kws  = (u16*)alloc((size_t)HH * TT * 64 * 2);
  u16* vTw  = (u16*)alloc((size_t)HH * VV * TT * 2);
  u16* aout = (u16*)alloc((size_t)TT * CC * 2);
  unsigned char* cidx_g = (unsigned char*)alloc(TT);
  u16* WrT      = (u16*)alloc((size_t)HH * 32 * 64 * 2);
  float* dW     = (float*)alloc((size_t)HH * 32 * 4);
  u16* o_part   = (u16*)alloc((size_t)SPLITS * HH * TT * VV * 2);
  float* m_part = (float*)alloc((size_t)SPLITS * HH * TT * 4);
  float* l_part = (float*)alloc((size_t)SPLITS * HH * TT * 4);

  prep_kernel<<<dim3(24, 24, 6), 256, 0, stream>>>(
      Wq, Wk, Wv, Wo, x, Wr, rwb, rrb,
      WqT, WkT, WvT, WoT, xbf, cidx_g, WrT, dW);
  gemm_qkv<<<dim3(40, 16), 256, 0, stream>>>(xbf, WqT, WkT, WvT,
                                             qw, Kws, vTw, rwb);
  attn_split<<<dim3(768), 256, 0, stream>>>(qw, Kws, vTw, WrT, dW, cidx_g,
                                            o_part, m_part, l_part);
  attn_combine<<<dim3(128, 8), 256, 0, stream>>>(o_part, m_part, l_part, aout);
  gemm_out<<<dim3(24, 16), 256, 0, stream>>>(aout, WoT, (float*)d_out, bo);
}

// Round 12
// 200.508 us; speedup vs baseline: 1.1088x; 1.0031x over previous
//
#include <hip/hip_runtime.h>
#include <hip/hip_bf16.h>

typedef unsigned short u16;
typedef unsigned int u32;
typedef __bf16 bf16_t;
typedef bf16_t bf16x8 __attribute__((ext_vector_type(8)));
typedef float fx4 __attribute__((ext_vector_type(4)));

#define TT 2048
#define HH 8
#define KK 64
#define VV 192
#define CC 1536
#define SPLITS 3
#define LOG2E 1.4426950408889634f

__device__ __forceinline__ float bf2f(u16 b) {
  union { u32 u; float f; } v; v.u = ((u32)b) << 16; return v.f;
}
__device__ __forceinline__ u16 f2bf(float f) {
  union { float f; u32 u; } v; v.f = f;
  return (u16)((v.u + 0x7FFFu + ((v.u >> 16) & 1u)) >> 16);
}
// native RNE cast -- pairs fuse to v_cvt_pk_bf16_f32 (attn hot path only)
__device__ __forceinline__ u16 f2bf_n(float f) {
  union { bf16_t b; u16 u; } v; v.b = (bf16_t)f; return v.u;
}
// fuses to v_max3_f32 (T17)
__device__ __forceinline__ float max3f(float a, float b, float c) {
  return fmaxf(fmaxf(a, b), c);
}
__device__ __forceinline__ fx4 mfma16(bf16x8 a, bf16x8 b, fx4 c) {
  return __builtin_amdgcn_mfma_f32_16x16x32_bf16(a, b, c, 0, 0, 0);
}
// async global->LDS, 16B/lane; LDS dest = wave-uniform base, lane*16 implicit
__device__ __forceinline__ void gl_lds16(const u16* g, u16* l) {
  __builtin_amdgcn_global_load_lds(
      (const __attribute__((address_space(1))) u32*)g,
      (__attribute__((address_space(3))) u32*)l, 16, 0, 0);
}

// ------ prep: weight transposes + cidx/WrT/dW tables + x conversion ----------
// z=0..3: weight transposes; z=4 (y==0, x=0/1/2 split): tables; z=5: x->bf16.
__global__ __launch_bounds__(256) void prep_kernel(
    const float* __restrict__ Wq, const float* __restrict__ Wk,
    const float* __restrict__ Wv, const float* __restrict__ Wo,
    const float* __restrict__ x, const float* __restrict__ Wr,
    const float* __restrict__ rwb, const float* __restrict__ rrb,
    u16* __restrict__ WqT, u16* __restrict__ WkT,
    u16* __restrict__ WvT, u16* __restrict__ WoT,
    u16* __restrict__ xbf, unsigned char* __restrict__ cidx_g,
    u16* __restrict__ WrT, float* __restrict__ dW) {
  const int z = blockIdx.z;
  const int t = threadIdx.x;
  if (z == 4) {
    if (blockIdx.y != 0 || blockIdx.x >= 3) return;
    if (blockIdx.x == 0) {
      // cidx: borzoi center-width category per |distance|
      float pr = expf(logf((float)(TT + 1)) / 16.0f);
      float cw[16];
      float wv = pr;
      for (int i = 0; i < 16; ++i) { cw[i] = wv - 1.0f; wv *= pr; }
      for (int idx = t; idx < TT; idx += 256) {
        int c = 15;
        for (int i = 14; i >= 0; --i)
          if (cw[i] > (float)idx) c = i;
        cidx_g[idx] = (unsigned char)c;
      }
    } else if (blockIdx.x == 1) {
      // WrT[h][i][k] bf16 from Wr f32 [32][512]
      for (int idx = t; idx < 8 * 32 * 64; idx += 256) {
        int hh = idx >> 11, rem = idx & 2047;
        int i = rem >> 6, k = rem & 63;
        WrT[idx] = f2bf(Wr[i * 512 + hh * 64 + k]);
      }
    } else {
      // dW[h*32+i] = sum_k (rrb - rwb)[h*64+k] * Wr[i][h*64+k]  (log2e-scaled)
      int hh = t >> 5, i = t & 31;
      float s = 0.0f;
      for (int k = 0; k < 64; ++k)
        s += (rrb[hh * 64 + k] - rwb[hh * 64 + k]) * Wr[i * 512 + hh * 64 + k];
      dW[t] = s * LOG2E;
    }
    return;
  }
  if (z == 5) {
    const size_t ngroups = (size_t)TT * CC / 8;
    int bid = blockIdx.y * 24 + blockIdx.x;  // 0..575
    for (size_t g = (size_t)bid * 256 + t; g < ngroups; g += (size_t)576 * 256) {
      size_t i = g * 8;
      float4 f0 = *(const float4*)&x[i];
      float4 f1 = *(const float4*)&x[i + 4];
      union { u16 h[8]; uint4 v; } pk;
      pk.h[0] = f2bf(f0.x); pk.h[1] = f2bf(f0.y);
      pk.h[2] = f2bf(f0.z); pk.h[3] = f2bf(f0.w);
      pk.h[4] = f2bf(f1.x); pk.h[5] = f2bf(f1.y);
      pk.h[6] = f2bf(f1.z); pk.h[7] = f2bf(f1.w);
      *(uint4*)&xbf[i] = pk.v;
    }
    return;
  }
  if (z < 2 && blockIdx.x >= 8) return;
  const float* in = (z == 0) ? Wq : (z == 1) ? Wk : (z == 2) ? Wv : Wo;
  u16* out = (z == 0) ? WqT : (z == 1) ? WkT : (z == 2) ? WvT : WoT;
  const int in_rs = (z < 2) ? 512 : 1536;
  const int out_rs = 1536;

  __shared__ u16 tile[64][68];
  const int c0 = blockIdx.x * 64, r0 = blockIdx.y * 64;
#pragma unroll
  for (int i = 0; i < 4; ++i) {
    int idx = i * 256 + t;
    int r = idx >> 4, ch = idx & 15;
    float4 fv = *(const float4*)&in[(size_t)(r0 + r) * in_rs + c0 + ch * 4];
    tile[r][ch * 4 + 0] = f2bf(fv.x);
    tile[r][ch * 4 + 1] = f2bf(fv.y);
    tile[r][ch * 4 + 2] = f2bf(fv.z);
    tile[r][ch * 4 + 3] = f2bf(fv.w);
  }
  __syncthreads();
#pragma unroll
  for (int i = 0; i < 4; ++i) {
    int idx = i * 256 + t;
    int r = idx >> 4, ch = idx & 15;
    u16 a0 = tile[ch * 4 + 0][r], a1 = tile[ch * 4 + 1][r];
    u16 a2 = tile[ch * 4 + 2][r], a3 = tile[ch * 4 + 3][r];
    uint2 d;
    d.x = (u32)a0 | ((u32)a1 << 16);
    d.y = (u32)a2 | ((u32)a3 << 16);
    *(uint2*)&out[(size_t)(c0 + r) * out_rs + r0 + ch * 4] = d;
  }
}

// ---------------- unified QKV projection GEMM (bf16 A) -----------------------
// ROUND-5 VERBATIM (verified on HW rounds 5/8/9; pipeline variants regressed
// or were unmeasurable). BM=128 BN=64 BK=64, dbuf LDS + 2-phase pipeline:
// STAGE(next) issued BEFORE compute(cur); one vmcnt(0)+s_barrier per k-step.
// Both-sides XOR swizzle (chunk^row&7) -> conflict-free ds_read_b128.
// grid (40,16): cb<8 -> Q (scale+bias, log2e), cb<16 -> K, else V (vT write).
__global__ __launch_bounds__(256) void gemm_qkv(
    const u16* __restrict__ xbf, const u16* __restrict__ WqT,
    const u16* __restrict__ WkT, const u16* __restrict__ WvT,
    u16* __restrict__ qw, u16* __restrict__ Kws, u16* __restrict__ vTw,
    const float* __restrict__ rwb) {
  __shared__ u16 As[2][128 * 64];  // 2 x 16 KB
  __shared__ u16 Bs[2][64 * 64];   // 2 x  8 KB
  const int cb = blockIdx.x;
  const u16* BT = (cb < 8) ? WqT : (cb < 16) ? WkT : WvT;
  const int n0 = ((cb < 8) ? cb : (cb < 16) ? cb - 8 : cb - 16) * 64;
  const int t = threadIdx.x;
  const int lane = t & 63, wid = t >> 6;
  const int l16 = lane & 15, quad = lane >> 4;
  const int wm = wid >> 1, wn = wid & 1;
  const int m0 = blockIdx.y * 128;
  const int wbase = wid * 512;  // wave-uniform LDS chunk base (u16 idx)

  auto stage = [&](int p, int k0) {
#pragma unroll
    for (int i = 0; i < 4; ++i) {
      int chunk = i * 256 + t;
      int r = chunk >> 3, c = (chunk & 7) ^ (r & 7);
      gl_lds16(&xbf[(size_t)(m0 + r) * CC + k0 + c * 8], &As[p][i * 2048 + wbase]);
    }
#pragma unroll
    for (int i = 0; i < 2; ++i) {
      int chunk = i * 256 + t;
      int r = chunk >> 3, c = (chunk & 7) ^ (r & 7);
      gl_lds16(&BT[(size_t)(n0 + r) * CC + k0 + c * 8], &Bs[p][i * 2048 + wbase]);
    }
  };

  fx4 acc[4][2] = {};
  stage(0, 0);
  asm volatile("s_waitcnt vmcnt(0)" ::: "memory");
  __builtin_amdgcn_s_barrier();
  int p = 0;
  for (int kt = 0; kt < 24; ++kt) {
    if (kt != 23) stage(p ^ 1, (kt + 1) * 64);
#pragma unroll
    for (int ks = 0; ks < 2; ++ks) {
      bf16x8 af[4], bfr[2];
#pragma unroll
      for (int mi = 0; mi < 4; ++mi) {
        int Ra = wm * 64 + mi * 16 + l16;
        af[mi] = *(const bf16x8*)&As[p][Ra * 64 + (((ks * 4 + quad) ^ (Ra & 7))) * 8];
      }
#pragma unroll
      for (int ni = 0; ni < 2; ++ni) {
        int Rb = wn * 32 + ni * 16 + l16;
        bfr[ni] = *(const bf16x8*)&Bs[p][Rb * 64 + (((ks * 4 + quad) ^ (Rb & 7))) * 8];
      }
#pragma unroll
      for (int mi = 0; mi < 4; ++mi)
#pragma unroll
        for (int ni = 0; ni < 2; ++ni)
          acc[mi][ni] = mfma16(af[mi], bfr[ni], acc[mi][ni]);
    }
    asm volatile("s_waitcnt vmcnt(0)" ::: "memory");
    __builtin_amdgcn_s_barrier();
    p ^= 1;
  }

#pragma unroll
  for (int mi = 0; mi < 4; ++mi)
#pragma unroll
    for (int ni = 0; ni < 2; ++ni) {
      int col = n0 + wn * 32 + ni * 16 + l16;
      int row0 = m0 + wm * 64 + mi * 16 + quad * 4;
      if (cb < 16) {
        int h = col >> 6, kx = col & 63;
#pragma unroll
        for (int r = 0; r < 4; ++r) {
          float v = acc[mi][ni][r];
          size_t o = ((size_t)h * TT + row0 + r) * 64 + kx;
          if (cb < 8) qw[o] = f2bf((v * 0.125f + rwb[col]) * LOG2E);
          else Kws[o] = f2bf(v);
        }
      } else {
        // direct transposed V write: vTw[h][vv][t], 4 consecutive t per lane
        // col is ALREADY rebased to [0,1536) via n0 = (cb-16)*64.
        int h = col / 192, vv = col - h * 192;
        union { u16 h4[4]; uint2 v2; } pk;
#pragma unroll
        for (int r = 0; r < 4; ++r) pk.h4[r] = f2bf(acc[mi][ni][r]);
        *(uint2*)&vTw[(size_t)h * VV * TT + (size_t)vv * TT + row0] = pk.v2;
      }
    }
}

// ---------------- out-projection GEMM: FLOAT out = A@WoT^T + bias ------------
// ROUND-5 VERBATIM. Same BM=128 BN=64 BK=64 dbuf pipeline. grid (24,16).
__global__ __launch_bounds__(256) void gemm_out(
    const u16* __restrict__ A, const u16* __restrict__ BT,
    float* __restrict__ out0, const float* __restrict__ bias0) {
  __shared__ u16 As[2][128 * 64];
  __shared__ u16 Bs[2][64 * 64];
  const int t = threadIdx.x;
  const int lane = t & 63, wid = t >> 6;
  const int l16 = lane & 15, quad = lane >> 4;
  const int wm = wid >> 1, wn = wid & 1;
  const int m0 = blockIdx.y * 128, n0 = blockIdx.x * 64;
  const int wbase = wid * 512;

  auto stage = [&](int p, int k0) {
#pragma unroll
    for (int i = 0; i < 4; ++i) {
      int chunk = i * 256 + t;
      int r = chunk >> 3, c = (chunk & 7) ^ (r & 7);
      gl_lds16(&A[(size_t)(m0 + r) * CC + k0 + c * 8], &As[p][i * 2048 + wbase]);
    }
#pragma unroll
    for (int i = 0; i < 2; ++i) {
      int chunk = i * 256 + t;
      int r = chunk >> 3, c = (chunk & 7) ^ (r & 7);
      gl_lds16(&BT[(size_t)(n0 + r) * CC + k0 + c * 8], &Bs[p][i * 2048 + wbase]);
    }
  };

  fx4 acc[4][2] = {};
  stage(0, 0);
  asm volatile("s_waitcnt vmcnt(0)" ::: "memory");
  __builtin_amdgcn_s_barrier();
  int p = 0;
  for (int kt = 0; kt < 24; ++kt) {
    if (kt != 23) stage(p ^ 1, (kt + 1) * 64);
#pragma unroll
    for (int ks = 0; ks < 2; ++ks) {
      bf16x8 af[4], bfr[2];
#pragma unroll
      for (int mi = 0; mi < 4; ++mi) {
        int Ra = wm * 64 + mi * 16 + l16;
        af[mi] = *(const bf16x8*)&As[p][Ra * 64 + (((ks * 4 + quad) ^ (Ra & 7))) * 8];
      }
#pragma unroll
      for (int ni = 0; ni < 2; ++ni) {
        int Rb = wn * 32 + ni * 16 + l16;
        bfr[ni] = *(const bf16x8*)&Bs[p][Rb * 64 + (((ks * 4 + quad) ^ (Rb & 7))) * 8];
      }
#pragma unroll
      for (int mi = 0; mi < 4; ++mi)
#pragma unroll
        for (int ni = 0; ni < 2; ++ni)
          acc[mi][ni] = mfma16(af[mi], bfr[ni], acc[mi][ni]);
    }
    asm volatile("s_waitcnt vmcnt(0)" ::: "memory");
    __builtin_amdgcn_s_barrier();
    p ^= 1;
  }
#pragma unroll
  for (int mi = 0; mi < 4; ++mi)
#pragma unroll
    for (int ni = 0; ni < 2; ++ni)
#pragma unroll
      for (int r = 0; r < 4; ++r) {
        int row = m0 + wm * 64 + mi * 16 + quad * 4 + r;
        int col = n0 + wn * 32 + ni * 16 + l16;
        out0[(size_t)row * CC + col] = acc[mi][ni][r] + bias0[col];
      }
}

// ---------------- split-K flash attention, LDS-staged K/V --------------------
// ROUND-9 structure (48.8us verified best) + max3f softmax reduction (T17).
// grid 768: h=blk&7 (XCD pin), ks=(blk>>3)%3, q0=((blk>>3)/3)*64.
// Counted waits: vmcnt(6) releases QK^T as soon as K lands; V latency hides
// under QK^T+rel+softmax; vmcnt(0) only before PV. Raw s_barriers (A/B/C).
// exp2-domain softmax, T13 defer-max, T5 setprio, native cvt_pk bf16 pack.
__global__ __launch_bounds__(256, 3) void attn_split(
    const u16* __restrict__ qw, const u16* __restrict__ Kw,
    const u16* __restrict__ vT, const u16* __restrict__ WrT,
    const float* __restrict__ dW, const unsigned char* __restrict__ cidx_g,
    u16* __restrict__ o_part, float* __restrict__ m_part,
    float* __restrict__ l_part) {
  const int blk = blockIdx.x;
  const int h = blk & 7;
  const int g = blk >> 3;
  const int ks = g % 3;
  const int q0 = (g / 3) * 64;
  const int t = threadIdx.x;
  const int lane = t & 63, w = t >> 6;
  const int l16 = lane & 15, quad = lane >> 4;

  __shared__ u16 KsL[64 * 64];         //  8192 B
  __shared__ u16 VsL[192 * 64];        // 24576 B
  __shared__ float2 UW[64][17];        //  8704 B
  __shared__ unsigned char cidx[TT];   //  2048 B
  __shared__ u16 Pl[4][16 * 72];       //  9216 B (u_raw scratch pre-loop)

  *(uint2*)&cidx[t * 8] = *(const uint2*)&cidx_g[t * 8];

  const int qloc = w * 16 + l16;
  const int q_abs = q0 + qloc;
  const u16* qp = qw + ((size_t)h * TT + q_abs) * 64 + quad * 8;
  const bf16x8 aq0 = *(const bf16x8*)qp;
  const bf16x8 aq1 = *(const bf16x8*)(qp + 32);

  // ---- UW build: u[q][i] = qw[q].WrT_h[i] + dW[h][i]; suffix sums ----
  {
    const u16* wrt = WrT + h * 32 * 64;
    bf16x8 wb00 = *(const bf16x8*)&wrt[l16 * 64 + quad * 8];
    bf16x8 wb01 = *(const bf16x8*)&wrt[l16 * 64 + 32 + quad * 8];
    bf16x8 wb10 = *(const bf16x8*)&wrt[(16 + l16) * 64 + quad * 8];
    bf16x8 wb11 = *(const bf16x8*)&wrt[(16 + l16) * 64 + 32 + quad * 8];
    fx4 u0 = {}, u1 = {};
    u0 = mfma16(aq0, wb00, u0); u0 = mfma16(aq1, wb01, u0);
    u1 = mfma16(aq0, wb10, u1); u1 = mfma16(aq1, wb11, u1);
    float dw0 = dW[h * 32 + l16], dw1 = dW[h * 32 + 16 + l16];
    float* u_raw = (float*)&Pl[0][0];   // [64][33]
#pragma unroll
    for (int r = 0; r < 4; ++r) {
      int qrow = w * 16 + quad * 4 + r;
      u_raw[qrow * 33 + l16] = u0[r] + dw0;
      u_raw[qrow * 33 + 16 + l16] = u1[r] + dw1;
    }
    __syncthreads();
    if (t < 64) {
      float su = 0.f, sw = 0.f;
      float Uv[16], Wv[16];
#pragma unroll
      for (int c = 15; c >= 0; --c) {
        su += u_raw[t * 33 + c]; Uv[c] = su;
        sw += u_raw[t * 33 + 16 + c]; Wv[c] = sw;
      }
#pragma unroll
      for (int c = 0; c < 16; ++c) UW[t][c] = make_float2(Uv[c], Wv[c]);
    }
  }
  __syncthreads();  // UW ready; u_raw scratch dead -> Pl reusable

  float m_s = -3.0e38f, l_s = 0.0f;
  fx4 o[12] = {};
  const u16* kbase = Kw + (size_t)h * TT * 64;
  const u16* vbase = vT + (size_t)h * VV * TT;
  const int jtab[4] = {0, 704, 1408, 2048};
  const int jbeg = jtab[ks], jfin = jtab[ks + 1];

  for (int j0 = jbeg; j0 < jfin; j0 += 64) {
    // (A) all waves done reading prev tile's KsL/VsL (PV precedes this)
    __builtin_amdgcn_s_barrier();
    // ---- async staging: K first (2 chunks/thr), then V (6 chunks/thr) ------
#pragma unroll
    for (int i = 0; i < 2; ++i) {
      int chunk = i * 256 + t;
      int j = chunk >> 3, c = (chunk & 7) ^ (j & 7);
      gl_lds16(&kbase[(size_t)(j0 + j) * 64 + c * 8],
               &KsL[(size_t)(i * 256 + w * 64) * 8]);
    }
#pragma unroll
    for (int i = 0; i < 6; ++i) {
      int chunk = i * 256 + t;
      int v = chunk >> 3, c = (chunk & 7) ^ (v & 7);
      gl_lds16(&vbase[(size_t)v * TT + j0 + c * 8],
               &VsL[(size_t)(i * 256 + w * 64) * 8]);
    }
    // ---- rel-term prep while loads are in flight ----
    const int dbase = j0 + quad * 4 - q_abs;
    int cc[16];
#pragma unroll
    for (int jt = 0; jt < 4; ++jt)
#pragma unroll
      for (int r = 0; r < 4; ++r) {
        int d = dbase + jt * 16 + r;
        cc[jt * 4 + r] = cidx[d < 0 ? -d : d];
      }
    float2 uwv[16];
#pragma unroll
    for (int i = 0; i < 16; ++i) uwv[i] = UW[qloc][cc[i]];
    // (B) our K chunks landed (oldest 2 of 8 outstanding); barrier -> all K in
    asm volatile("s_waitcnt vmcnt(6)" ::: "memory");
    __builtin_amdgcn_s_barrier();
    __builtin_amdgcn_sched_barrier(0);
    // ---- K fragments from LDS, S^T = K.Q^T ----
    bf16x8 kf[8];
#pragma unroll
    for (int jt = 0; jt < 4; ++jt) {
      int j = jt * 16 + l16;
      kf[jt * 2]     = *(const bf16x8*)&KsL[j * 64 + ((quad) ^ (j & 7)) * 8];
      kf[jt * 2 + 1] = *(const bf16x8*)&KsL[j * 64 + ((quad + 4) ^ (j & 7)) * 8];
    }
    fx4 s[4];
    __builtin_amdgcn_s_setprio(1);
#pragma unroll
    for (int jt = 0; jt < 4; ++jt) {
      fx4 z = {0.f, 0.f, 0.f, 0.f};
      z = mfma16(kf[jt * 2], aq0, z);
      s[jt] = mfma16(kf[jt * 2 + 1], aq1, z);
    }
    __builtin_amdgcn_s_setprio(0);
#pragma unroll
    for (int jt = 0; jt < 4; ++jt)
#pragma unroll
      for (int r = 0; r < 4; ++r) {
        int d = dbase + jt * 16 + r;
        float2 z = uwv[jt * 4 + r];
        s[jt][r] += z.x + (d > 0 ? z.y : (d < 0 ? -z.y : 0.0f));
      }
    // ---- per-lane online softmax (exp2 domain); max via v_max3 tree ----
    float ma = max3f(s[0][0], s[0][1], s[0][2]);
    float mb = max3f(s[0][3], s[1][0], s[1][1]);
    float mc = max3f(s[1][2], s[1][3], s[2][0]);
    float md = max3f(s[2][1], s[2][2], s[2][3]);
    float me = max3f(s[3][0], s[3][1], s[3][2]);
    float mx = max3f(ma, mb, mc);
    mx = max3f(mx, md, me);
    mx = fmaxf(mx, s[3][3]);
    mx = fmaxf(mx, __shfl_xor(mx, 16, 64));
    mx = fmaxf(mx, __shfl_xor(mx, 32, 64));
    if (!__all(mx - m_s <= 8.0f)) {   // T13: rescale only on real max growth
      float mnew = fmaxf(m_s, mx);
      float alpha = exp2f(m_s - mnew);
      float a4[4];
#pragma unroll
      for (int r = 0; r < 4; ++r) a4[r] = __shfl(alpha, quad * 4 + r, 16);
#pragma unroll
      for (int vt = 0; vt < 12; ++vt)
#pragma unroll
        for (int r = 0; r < 4; ++r) o[vt][r] *= a4[r];
      l_s *= alpha;
      m_s = mnew;
    }
    float p16[16];
    float ps = 0.0f;
#pragma unroll
    for (int jt = 0; jt < 4; ++jt)
#pragma unroll
      for (int r = 0; r < 4; ++r) {
        float p = exp2f(s[jt][r] - m_s);
        p16[jt * 4 + r] = p;
        ps += p;
      }
    ps += __shfl_xor(ps, 16, 64);
    ps += __shfl_xor(ps, 32, 64);
    l_s += ps;
    // ---- P -> LDS (wave-private) -> A-operand (native cvt_pk pack) ----
#pragma unroll
    for (int jt = 0; jt < 4; ++jt) {
      union { u16 h4[4]; uint2 v; } pk;
#pragma unroll
      for (int r = 0; r < 4; ++r) pk.h4[r] = f2bf_n(p16[jt * 4 + r]);
      *(uint2*)&Pl[w][l16 * 72 + jt * 16 + quad * 4] = pk.v;
    }
    asm volatile("s_waitcnt lgkmcnt(0)" ::: "memory");
    bf16x8 pf0 = *(const bf16x8*)&Pl[w][l16 * 72 + quad * 8];
    bf16x8 pf1 = *(const bf16x8*)&Pl[w][l16 * 72 + 32 + quad * 8];
    // (C) all V chunks landed everywhere; latency hidden under the above
    asm volatile("s_waitcnt vmcnt(0)" ::: "memory");
    __builtin_amdgcn_s_barrier();
    __builtin_amdgcn_sched_barrier(0);
    // ---- PV from LDS V tile ----
    __builtin_amdgcn_s_setprio(1);
#pragma unroll
    for (int vt = 0; vt < 12; ++vt) {
      int v = vt * 16 + l16;
      bf16x8 bv = *(const bf16x8*)&VsL[v * 64 + ((quad) ^ (v & 7)) * 8];
      o[vt] = mfma16(pf0, bv, o[vt]);
    }
#pragma unroll
    for (int vt = 0; vt < 12; ++vt) {
      int v = vt * 16 + l16;
      bf16x8 bv = *(const bf16x8*)&VsL[v * 64 + ((quad + 4) ^ (v & 7)) * 8];
      o[vt] = mfma16(pf1, bv, o[vt]);
    }
    __builtin_amdgcn_s_setprio(0);
  }

#pragma unroll
  for (int r = 0; r < 4; ++r) {
    int row = q0 + w * 16 + quad * 4 + r;
    size_t base = ((size_t)(ks * HH + h) * TT + row) * VV;
#pragma unroll
    for (int vt = 0; vt < 12; ++vt) o_part[base + vt * 16 + l16] = f2bf_n(o[vt][r]);
  }
  if (quad == 0) {
    m_part[(size_t)(ks * HH + h) * TT + q_abs] = m_s;
    l_part[(size_t)(ks * HH + h) * TT + q_abs] = l_s;
  }
}

// ---------------- combine split-K partials -> bf16 aout ----------------------
// m_part is in log2 domain -> exp2f weights.
__global__ __launch_bounds__(256) void attn_combine(
    const u16* __restrict__ o_part, const float* __restrict__ m_part,
    const float* __restrict__ l_part, u16* __restrict__ aout) {
  const int h = blockIdx.y;
  const int row = blockIdx.x * 16 + (threadIdx.x >> 4);
  const int c0 = (threadIdx.x & 15) * 12;

  float m[SPLITS], M = -3.0e38f;
#pragma unroll
  for (int s = 0; s < SPLITS; ++s) {
    m[s] = m_part[(size_t)(s * HH + h) * TT + row];
    M = fmaxf(M, m[s]);
  }
  float lsum = 0.0f, wgt[SPLITS];
#pragma unroll
  for (int s = 0; s < SPLITS; ++s) {
    wgt[s] = exp2f(m[s] - M);
    lsum += wgt[s] * l_part[(size_t)(s * HH + h) * TT + row];
  }
  float o[12];
#pragma unroll
  for (int j = 0; j < 12; ++j) o[j] = 0.0f;
#pragma unroll
  for (int s = 0; s < SPLITS; ++s) {
    const u16* op = o_part + ((size_t)(s * HH + h) * TT + row) * VV + c0;
    float wgts = wgt[s];
    uint2 u0 = *(const uint2*)&op[0];
    uint2 u1 = *(const uint2*)&op[4];
    uint2 u2 = *(const uint2*)&op[8];
    u32 uu[6] = {u0.x, u0.y, u1.x, u1.y, u2.x, u2.y};
#pragma unroll
    for (int j = 0; j < 6; ++j) {
      o[j * 2 + 0] = fmaf(wgts, bf2f((u16)(uu[j] & 0xFFFF)), o[j * 2 + 0]);
      o[j * 2 + 1] = fmaf(wgts, bf2f((u16)(uu[j] >> 16)), o[j * 2 + 1]);
    }
  }
  float inv = 1.0f / lsum;
  union { u16 hx[12]; uint2 v2[3]; } pk;
#pragma unroll
  for (int j = 0; j < 12; ++j) pk.hx[j] = f2bf(o[j] * inv);
  u16* dst = aout + (size_t)row * CC + h * VV + c0;
  *(uint2*)&dst[0] = pk.v2[0];
  *(uint2*)&dst[4] = pk.v2[1];
  *(uint2*)&dst[8] = pk.v2[2];
}

extern "C" void kernel_launch(void* const* d_in, const int* in_sizes, int n_in,
                              void* d_out, int out_size, void* d_ws, size_t ws_size,
                              hipStream_t stream) {
  (void)in_sizes; (void)n_in; (void)out_size; (void)ws_size;
  const float* x   = (const float*)d_in[0];
  const float* Wq  = (const float*)d_in[1];
  const float* Wk  = (const float*)d_in[2];
  const float* Wv  = (const float*)d_in[3];
  const float* Wr  = (const float*)d_in[4];
  const float* rwb = (const float*)d_in[5];
  const float* rrb = (const float*)d_in[6];
  const float* Wo  = (const float*)d_in[7];
  const float* bo  = (const float*)d_in[8];

  char* ws = (char*)d_ws;
  size_t off = 0;
  auto alloc = [&](size_t bytes) -> void* {
    void* p = ws + off;
    off += (bytes + 255) & ~(size_t)255;
    return p;
  };
  u16* WqT  = (u16*)alloc((size_t)512 * 1536 * 2);
  u16* WkT  = (u16*)alloc((size_t)512 * 1536 * 2);
  u16* WvT  = (u16*)alloc((size_t)1536 * 1536 * 2);
  u16* WoT  = (u16*)alloc((size_t)1536 * 1536 * 2);
  u16* xbf  = (u16*)alloc((size_t)TT * CC * 2);
  u16* qw   = (u16*)alloc((size_t)HH * TT * 64 * 2);
  u16* Kws  = (u16*)alloc((size_t)HH * TT * 64 * 2);
  u16* vTw  = (u16*)alloc((size_t)HH * VV * TT * 2);
  u16* aout = (u16*)alloc((size_t)TT * CC * 2);
  unsigned char* cidx_g = (unsigned char*)alloc(TT);
  u16* WrT      = (u16*)alloc((size_t)HH * 32 * 64 * 2);
  float* dW     = (float*)alloc((size_t)HH * 32 * 4);
  u16* o_part   = (u16*)alloc((size_t)SPLITS * HH * TT * VV * 2);
  float* m_part = (float*)alloc((size_t)SPLITS * HH * TT * 4);
  float* l_part = (float*)alloc((size_t)SPLITS * HH * TT * 4);

  prep_kernel<<<dim3(24, 24, 6), 256, 0, stream>>>(
      Wq, Wk, Wv, Wo, x, Wr, rwb, rrb,
      WqT, WkT, WvT, WoT, xbf, cidx_g, WrT, dW);
  gemm_qkv<<<dim3(40, 16), 256, 0, stream>>>(xbf, WqT, WkT, WvT,
                                             qw, Kws, vTw, rwb);
  attn_split<<<dim3(768), 256, 0, stream>>>(qw, Kws, vTw, WrT, dW, cidx_g,
                                            o_part, m_part, l_part);
  attn_combine<<<dim3(128, 8), 256, 0, stream>>>(o_part, m_part, l_part, aout);
  gemm_out<<<dim3(24, 16), 256, 0, stream>>>(aout, WoT, (float*)d_out, bo);
}

// Round 13
// 197.877 us; speedup vs baseline: 1.1235x; 1.0133x over previous
//
#include <hip/hip_runtime.h>
#include <hip/hip_bf16.h>

typedef unsigned short u16;
typedef unsigned int u32;
typedef __bf16 bf16_t;
typedef bf16_t bf16x8 __attribute__((ext_vector_type(8)));
typedef float fx4 __attribute__((ext_vector_type(4)));

#define TT 2048
#define HH 8
#define KK 64
#define VV 192
#define CC 1536
#define SPLITS 3
#define LOG2E 1.4426950408889634f

__device__ __forceinline__ float bf2f(u16 b) {
  union { u32 u; float f; } v; v.u = ((u32)b) << 16; return v.f;
}
__device__ __forceinline__ u16 f2bf(float f) {
  union { float f; u32 u; } v; v.f = f;
  return (u16)((v.u + 0x7FFFu + ((v.u >> 16) & 1u)) >> 16);
}
// native RNE cast -- pairs fuse to v_cvt_pk_bf16_f32 (attn hot path only)
__device__ __forceinline__ u16 f2bf_n(float f) {
  union { bf16_t b; u16 u; } v; v.b = (bf16_t)f; return v.u;
}
// fuses to v_max3_f32 (T17)
__device__ __forceinline__ float max3f(float a, float b, float c) {
  return fmaxf(fmaxf(a, b), c);
}
__device__ __forceinline__ fx4 mfma16(bf16x8 a, bf16x8 b, fx4 c) {
  return __builtin_amdgcn_mfma_f32_16x16x32_bf16(a, b, c, 0, 0, 0);
}
// async global->LDS, 16B/lane; LDS dest = wave-uniform base, lane*16 implicit
__device__ __forceinline__ void gl_lds16(const u16* g, u16* l) {
  __builtin_amdgcn_global_load_lds(
      (const __attribute__((address_space(1))) u32*)g,
      (__attribute__((address_space(3))) u32*)l, 16, 0, 0);
}

// ------ prep: weight transposes + cidx/WrT/dW tables + x conversion ----------
// z=0..3: weight transposes; z=4 (y==0, x=0/1/2 split): tables; z=5: x->bf16.
__global__ __launch_bounds__(256) void prep_kernel(
    const float* __restrict__ Wq, const float* __restrict__ Wk,
    const float* __restrict__ Wv, const float* __restrict__ Wo,
    const float* __restrict__ x, const float* __restrict__ Wr,
    const float* __restrict__ rwb, const float* __restrict__ rrb,
    u16* __restrict__ WqT, u16* __restrict__ WkT,
    u16* __restrict__ WvT, u16* __restrict__ WoT,
    u16* __restrict__ xbf, unsigned char* __restrict__ cidx_g,
    u16* __restrict__ WrT, float* __restrict__ dW) {
  const int z = blockIdx.z;
  const int t = threadIdx.x;
  if (z == 4) {
    if (blockIdx.y != 0 || blockIdx.x >= 3) return;
    if (blockIdx.x == 0) {
      // cidx: borzoi center-width category per |distance|
      float pr = expf(logf((float)(TT + 1)) / 16.0f);
      float cw[16];
      float wv = pr;
      for (int i = 0; i < 16; ++i) { cw[i] = wv - 1.0f; wv *= pr; }
      for (int idx = t; idx < TT; idx += 256) {
        int c = 15;
        for (int i = 14; i >= 0; --i)
          if (cw[i] > (float)idx) c = i;
        cidx_g[idx] = (unsigned char)c;
      }
    } else if (blockIdx.x == 1) {
      // WrT[h][i][k] bf16 from Wr f32 [32][512]
      for (int idx = t; idx < 8 * 32 * 64; idx += 256) {
        int hh = idx >> 11, rem = idx & 2047;
        int i = rem >> 6, k = rem & 63;
        WrT[idx] = f2bf(Wr[i * 512 + hh * 64 + k]);
      }
    } else {
      // dW[h*32+i] = sum_k (rrb - rwb)[h*64+k] * Wr[i][h*64+k]  (log2e-scaled)
      int hh = t >> 5, i = t & 31;
      float s = 0.0f;
      for (int k = 0; k < 64; ++k)
        s += (rrb[hh * 64 + k] - rwb[hh * 64 + k]) * Wr[i * 512 + hh * 64 + k];
      dW[t] = s * LOG2E;
    }
    return;
  }
  if (z == 5) {
    const size_t ngroups = (size_t)TT * CC / 8;
    int bid = blockIdx.y * 24 + blockIdx.x;  // 0..575
    for (size_t g = (size_t)bid * 256 + t; g < ngroups; g += (size_t)576 * 256) {
      size_t i = g * 8;
      float4 f0 = *(const float4*)&x[i];
      float4 f1 = *(const float4*)&x[i + 4];
      union { u16 h[8]; uint4 v; } pk;
      pk.h[0] = f2bf(f0.x); pk.h[1] = f2bf(f0.y);
      pk.h[2] = f2bf(f0.z); pk.h[3] = f2bf(f0.w);
      pk.h[4] = f2bf(f1.x); pk.h[5] = f2bf(f1.y);
      pk.h[6] = f2bf(f1.z); pk.h[7] = f2bf(f1.w);
      *(uint4*)&xbf[i] = pk.v;
    }
    return;
  }
  if (z < 2 && blockIdx.x >= 8) return;
  const float* in = (z == 0) ? Wq : (z == 1) ? Wk : (z == 2) ? Wv : Wo;
  u16* out = (z == 0) ? WqT : (z == 1) ? WkT : (z == 2) ? WvT : WoT;
  const int in_rs = (z < 2) ? 512 : 1536;
  const int out_rs = 1536;

  __shared__ u16 tile[64][68];
  const int c0 = blockIdx.x * 64, r0 = blockIdx.y * 64;
#pragma unroll
  for (int i = 0; i < 4; ++i) {
    int idx = i * 256 + t;
    int r = idx >> 4, ch = idx & 15;
    float4 fv = *(const float4*)&in[(size_t)(r0 + r) * in_rs + c0 + ch * 4];
    tile[r][ch * 4 + 0] = f2bf(fv.x);
    tile[r][ch * 4 + 1] = f2bf(fv.y);
    tile[r][ch * 4 + 2] = f2bf(fv.z);
    tile[r][ch * 4 + 3] = f2bf(fv.w);
  }
  __syncthreads();
#pragma unroll
  for (int i = 0; i < 4; ++i) {
    int idx = i * 256 + t;
    int r = idx >> 4, ch = idx & 15;
    u16 a0 = tile[ch * 4 + 0][r], a1 = tile[ch * 4 + 1][r];
    u16 a2 = tile[ch * 4 + 2][r], a3 = tile[ch * 4 + 3][r];
    uint2 d;
    d.x = (u32)a0 | ((u32)a1 << 16);
    d.y = (u32)a2 | ((u32)a3 << 16);
    *(uint2*)&out[(size_t)(c0 + r) * out_rs + r0 + ch * 4] = d;
  }
}

// ---------------- unified QKV projection GEMM (bf16 A) -----------------------
// ROUND-5 VERBATIM (frozen known-good). BM=128 BN=64 BK=64, dbuf LDS +
// 2-phase pipeline: STAGE(next) BEFORE compute(cur); one vmcnt(0)+s_barrier
// per k-step. Both-sides XOR swizzle -> conflict-free ds_read_b128.
// grid (40,16): cb<8 -> Q (scale+bias, log2e), cb<16 -> K, else V (vT write).
__global__ __launch_bounds__(256) void gemm_qkv(
    const u16* __restrict__ xbf, const u16* __restrict__ WqT,
    const u16* __restrict__ WkT, const u16* __restrict__ WvT,
    u16* __restrict__ qw, u16* __restrict__ Kws, u16* __restrict__ vTw,
    const float* __restrict__ rwb) {
  __shared__ u16 As[2][128 * 64];  // 2 x 16 KB
  __shared__ u16 Bs[2][64 * 64];   // 2 x  8 KB
  const int cb = blockIdx.x;
  const u16* BT = (cb < 8) ? WqT : (cb < 16) ? WkT : WvT;
  const int n0 = ((cb < 8) ? cb : (cb < 16) ? cb - 8 : cb - 16) * 64;
  const int t = threadIdx.x;
  const int lane = t & 63, wid = t >> 6;
  const int l16 = lane & 15, quad = lane >> 4;
  const int wm = wid >> 1, wn = wid & 1;
  const int m0 = blockIdx.y * 128;
  const int wbase = wid * 512;  // wave-uniform LDS chunk base (u16 idx)

  auto stage = [&](int p, int k0) {
#pragma unroll
    for (int i = 0; i < 4; ++i) {
      int chunk = i * 256 + t;
      int r = chunk >> 3, c = (chunk & 7) ^ (r & 7);
      gl_lds16(&xbf[(size_t)(m0 + r) * CC + k0 + c * 8], &As[p][i * 2048 + wbase]);
    }
#pragma unroll
    for (int i = 0; i < 2; ++i) {
      int chunk = i * 256 + t;
      int r = chunk >> 3, c = (chunk & 7) ^ (r & 7);
      gl_lds16(&BT[(size_t)(n0 + r) * CC + k0 + c * 8], &Bs[p][i * 2048 + wbase]);
    }
  };

  fx4 acc[4][2] = {};
  stage(0, 0);
  asm volatile("s_waitcnt vmcnt(0)" ::: "memory");
  __builtin_amdgcn_s_barrier();
  int p = 0;
  for (int kt = 0; kt < 24; ++kt) {
    if (kt != 23) stage(p ^ 1, (kt + 1) * 64);
#pragma unroll
    for (int ks = 0; ks < 2; ++ks) {
      bf16x8 af[4], bfr[2];
#pragma unroll
      for (int mi = 0; mi < 4; ++mi) {
        int Ra = wm * 64 + mi * 16 + l16;
        af[mi] = *(const bf16x8*)&As[p][Ra * 64 + (((ks * 4 + quad) ^ (Ra & 7))) * 8];
      }
#pragma unroll
      for (int ni = 0; ni < 2; ++ni) {
        int Rb = wn * 32 + ni * 16 + l16;
        bfr[ni] = *(const bf16x8*)&Bs[p][Rb * 64 + (((ks * 4 + quad) ^ (Rb & 7))) * 8];
      }
#pragma unroll
      for (int mi = 0; mi < 4; ++mi)
#pragma unroll
        for (int ni = 0; ni < 2; ++ni)
          acc[mi][ni] = mfma16(af[mi], bfr[ni], acc[mi][ni]);
    }
    asm volatile("s_waitcnt vmcnt(0)" ::: "memory");
    __builtin_amdgcn_s_barrier();
    p ^= 1;
  }

#pragma unroll
  for (int mi = 0; mi < 4; ++mi)
#pragma unroll
    for (int ni = 0; ni < 2; ++ni) {
      int col = n0 + wn * 32 + ni * 16 + l16;
      int row0 = m0 + wm * 64 + mi * 16 + quad * 4;
      if (cb < 16) {
        int h = col >> 6, kx = col & 63;
#pragma unroll
        for (int r = 0; r < 4; ++r) {
          float v = acc[mi][ni][r];
          size_t o = ((size_t)h * TT + row0 + r) * 64 + kx;
          if (cb < 8) qw[o] = f2bf((v * 0.125f + rwb[col]) * LOG2E);
          else Kws[o] = f2bf(v);
        }
      } else {
        // direct transposed V write: vTw[h][vv][t], 4 consecutive t per lane
        // col is ALREADY rebased to [0,1536) via n0 = (cb-16)*64.
        int h = col / 192, vv = col - h * 192;
        union { u16 h4[4]; uint2 v2; } pk;
#pragma unroll
        for (int r = 0; r < 4; ++r) pk.h4[r] = f2bf(acc[mi][ni][r]);
        *(uint2*)&vTw[(size_t)h * VV * TT + (size_t)vv * TT + row0] = pk.v2;
      }
    }
}

// ---------------- out-projection GEMM: FLOAT out = A@WoT^T + bias ------------
// ROUND-5 VERBATIM. Same BM=128 BN=64 BK=64 dbuf pipeline. grid (24,16).
__global__ __launch_bounds__(256) void gemm_out(
    const u16* __restrict__ A, const u16* __restrict__ BT,
    float* __restrict__ out0, const float* __restrict__ bias0) {
  __shared__ u16 As[2][128 * 64];
  __shared__ u16 Bs[2][64 * 64];
  const int t = threadIdx.x;
  const int lane = t & 63, wid = t >> 6;
  const int l16 = lane & 15, quad = lane >> 4;
  const int wm = wid >> 1, wn = wid & 1;
  const int m0 = blockIdx.y * 128, n0 = blockIdx.x * 64;
  const int wbase = wid * 512;

  auto stage = [&](int p, int k0) {
#pragma unroll
    for (int i = 0; i < 4; ++i) {
      int chunk = i * 256 + t;
      int r = chunk >> 3, c = (chunk & 7) ^ (r & 7);
      gl_lds16(&A[(size_t)(m0 + r) * CC + k0 + c * 8], &As[p][i * 2048 + wbase]);
    }
#pragma unroll
    for (int i = 0; i < 2; ++i) {
      int chunk = i * 256 + t;
      int r = chunk >> 3, c = (chunk & 7) ^ (r & 7);
      gl_lds16(&BT[(size_t)(n0 + r) * CC + k0 + c * 8], &Bs[p][i * 2048 + wbase]);
    }
  };

  fx4 acc[4][2] = {};
  stage(0, 0);
  asm volatile("s_waitcnt vmcnt(0)" ::: "memory");
  __builtin_amdgcn_s_barrier();
  int p = 0;
  for (int kt = 0; kt < 24; ++kt) {
    if (kt != 23) stage(p ^ 1, (kt + 1) * 64);
#pragma unroll
    for (int ks = 0; ks < 2; ++ks) {
      bf16x8 af[4], bfr[2];
#pragma unroll
      for (int mi = 0; mi < 4; ++mi) {
        int Ra = wm * 64 + mi * 16 + l16;
        af[mi] = *(const bf16x8*)&As[p][Ra * 64 + (((ks * 4 + quad) ^ (Ra & 7))) * 8];
      }
#pragma unroll
      for (int ni = 0; ni < 2; ++ni) {
        int Rb = wn * 32 + ni * 16 + l16;
        bfr[ni] = *(const bf16x8*)&Bs[p][Rb * 64 + (((ks * 4 + quad) ^ (Rb & 7))) * 8];
      }
#pragma unroll
      for (int mi = 0; mi < 4; ++mi)
#pragma unroll
        for (int ni = 0; ni < 2; ++ni)
          acc[mi][ni] = mfma16(af[mi], bfr[ni], acc[mi][ni]);
    }
    asm volatile("s_waitcnt vmcnt(0)" ::: "memory");
    __builtin_amdgcn_s_barrier();
    p ^= 1;
  }
#pragma unroll
  for (int mi = 0; mi < 4; ++mi)
#pragma unroll
    for (int ni = 0; ni < 2; ++ni)
#pragma unroll
      for (int r = 0; r < 4; ++r) {
        int row = m0 + wm * 64 + mi * 16 + quad * 4 + r;
        int col = n0 + wn * 32 + ni * 16 + l16;
        out0[(size_t)row * CC + col] = acc[mi][ni][r] + bias0[col];
      }
}

// ---------------- split-K flash attention, LDS-staged K/V --------------------
// ROUND-12 math (45.8us verified) with K staged ONE TILE AHEAD -> 2 barriers
// per tile (was 3), QK^T starts with ZERO wait.
//   barrier A: VsL free (all PV reads done) + K(j) landed by all waves
//              (every wave did post-PV vmcnt(0) on its own K chunks).
//   barrier C: all V in; also certifies all KsL reads done (kf reads precede
//              P-pack in program order) -> safe to restage KsL after C.
// K(j+1) issue sits between C and PV; its latency hides under PV (~1200cy);
// post-PV vmcnt(0) is ~free. Single KsL buffer, same LDS, same occupancy.
// grid 768: h=blk&7 (XCD pin), ks=(blk>>3)%3, q0=((blk>>3)/3)*64.
// exp2-domain softmax, T13 defer-max, T5 setprio, v_max3 tree, cvt_pk pack.
__global__ __launch_bounds__(256, 3) void attn_split(
    const u16* __restrict__ qw, const u16* __restrict__ Kw,
    const u16* __restrict__ vT, const u16* __restrict__ WrT,
    const float* __restrict__ dW, const unsigned char* __restrict__ cidx_g,
    u16* __restrict__ o_part, float* __restrict__ m_part,
    float* __restrict__ l_part) {
  const int blk = blockIdx.x;
  const int h = blk & 7;
  const int g = blk >> 3;
  const int ks = g % 3;
  const int q0 = (g / 3) * 64;
  const int t = threadIdx.x;
  const int lane = t & 63, w = t >> 6;
  const int l16 = lane & 15, quad = lane >> 4;

  __shared__ u16 KsL[64 * 64];         //  8192 B
  __shared__ u16 VsL[192 * 64];        // 24576 B
  __shared__ float2 UW[64][17];        //  8704 B
  __shared__ unsigned char cidx[TT];   //  2048 B
  __shared__ u16 Pl[4][16 * 72];       //  9216 B (u_raw scratch pre-loop)

  *(uint2*)&cidx[t * 8] = *(const uint2*)&cidx_g[t * 8];

  const int qloc = w * 16 + l16;
  const int q_abs = q0 + qloc;
  const u16* qp = qw + ((size_t)h * TT + q_abs) * 64 + quad * 8;
  const bf16x8 aq0 = *(const bf16x8*)qp;
  const bf16x8 aq1 = *(const bf16x8*)(qp + 32);

  // ---- UW build: u[q][i] = qw[q].WrT_h[i] + dW[h][i]; suffix sums ----
  {
    const u16* wrt = WrT + h * 32 * 64;
    bf16x8 wb00 = *(const bf16x8*)&wrt[l16 * 64 + quad * 8];
    bf16x8 wb01 = *(const bf16x8*)&wrt[l16 * 64 + 32 + quad * 8];
    bf16x8 wb10 = *(const bf16x8*)&wrt[(16 + l16) * 64 + quad * 8];
    bf16x8 wb11 = *(const bf16x8*)&wrt[(16 + l16) * 64 + 32 + quad * 8];
    fx4 u0 = {}, u1 = {};
    u0 = mfma16(aq0, wb00, u0); u0 = mfma16(aq1, wb01, u0);
    u1 = mfma16(aq0, wb10, u1); u1 = mfma16(aq1, wb11, u1);
    float dw0 = dW[h * 32 + l16], dw1 = dW[h * 32 + 16 + l16];
    float* u_raw = (float*)&Pl[0][0];   // [64][33]
#pragma unroll
    for (int r = 0; r < 4; ++r) {
      int qrow = w * 16 + quad * 4 + r;
      u_raw[qrow * 33 + l16] = u0[r] + dw0;
      u_raw[qrow * 33 + 16 + l16] = u1[r] + dw1;
    }
    __syncthreads();
    if (t < 64) {
      float su = 0.f, sw = 0.f;
      float Uv[16], Wv[16];
#pragma unroll
      for (int c = 15; c >= 0; --c) {
        su += u_raw[t * 33 + c]; Uv[c] = su;
        sw += u_raw[t * 33 + 16 + c]; Wv[c] = sw;
      }
#pragma unroll
      for (int c = 0; c < 16; ++c) UW[t][c] = make_float2(Uv[c], Wv[c]);
    }
  }
  __syncthreads();  // UW ready; u_raw scratch dead -> Pl reusable

  float m_s = -3.0e38f, l_s = 0.0f;
  fx4 o[12] = {};
  const u16* kbase = Kw + (size_t)h * TT * 64;
  const u16* vbase = vT + (size_t)h * VV * TT;
  const int jtab[4] = {0, 704, 1408, 2048};
  const int jbeg = jtab[ks], jfin = jtab[ks + 1];

  // ---- prologue: stage K(first tile); own chunks landed before loop ----
#pragma unroll
  for (int i = 0; i < 2; ++i) {
    int chunk = i * 256 + t;
    int j = chunk >> 3, c = (chunk & 7) ^ (j & 7);
    gl_lds16(&kbase[(size_t)(jbeg + j) * 64 + c * 8],
             &KsL[(size_t)(i * 256 + w * 64) * 8]);
  }
  asm volatile("s_waitcnt vmcnt(0)" ::: "memory");

  for (int j0 = jbeg; j0 < jfin; j0 += 64) {
    // (A) VsL free (all waves' PV reads done) + K(j0) staged by all waves
    __builtin_amdgcn_s_barrier();
    // ---- async V staging: 6 chunks/thr ----
#pragma unroll
    for (int i = 0; i < 6; ++i) {
      int chunk = i * 256 + t;
      int v = chunk >> 3, c = (chunk & 7) ^ (v & 7);
      gl_lds16(&vbase[(size_t)v * TT + j0 + c * 8],
               &VsL[(size_t)(i * 256 + w * 64) * 8]);
    }
    // ---- rel-term prep while V loads are in flight ----
    const int dbase = j0 + quad * 4 - q_abs;
    int cc[16];
#pragma unroll
    for (int jt = 0; jt < 4; ++jt)
#pragma unroll
      for (int r = 0; r < 4; ++r) {
        int d = dbase + jt * 16 + r;
        cc[jt * 4 + r] = cidx[d < 0 ? -d : d];
      }
    float2 uwv[16];
#pragma unroll
    for (int i = 0; i < 16; ++i) uwv[i] = UW[qloc][cc[i]];
    // ---- K fragments from LDS (resident since prev tile), S^T = K.Q^T ----
    bf16x8 kf[8];
#pragma unroll
    for (int jt = 0; jt < 4; ++jt) {
      int j = jt * 16 + l16;
      kf[jt * 2]     = *(const bf16x8*)&KsL[j * 64 + ((quad) ^ (j & 7)) * 8];
      kf[jt * 2 + 1] = *(const bf16x8*)&KsL[j * 64 + ((quad + 4) ^ (j & 7)) * 8];
    }
    fx4 s[4];
    __builtin_amdgcn_s_setprio(1);
#pragma unroll
    for (int jt = 0; jt < 4; ++jt) {
      fx4 z = {0.f, 0.f, 0.f, 0.f};
      z = mfma16(kf[jt * 2], aq0, z);
      s[jt] = mfma16(kf[jt * 2 + 1], aq1, z);
    }
    __builtin_amdgcn_s_setprio(0);
#pragma unroll
    for (int jt = 0; jt < 4; ++jt)
#pragma unroll
      for (int r = 0; r < 4; ++r) {
        int d = dbase + jt * 16 + r;
        float2 z = uwv[jt * 4 + r];
        s[jt][r] += z.x + (d > 0 ? z.y : (d < 0 ? -z.y : 0.0f));
      }
    // ---- per-lane online softmax (exp2 domain); max via v_max3 tree ----
    float ma = max3f(s[0][0], s[0][1], s[0][2]);
    float mb = max3f(s[0][3], s[1][0], s[1][1]);
    float mc = max3f(s[1][2], s[1][3], s[2][0]);
    float md = max3f(s[2][1], s[2][2], s[2][3]);
    float me = max3f(s[3][0], s[3][1], s[3][2]);
    float mx = max3f(ma, mb, mc);
    mx = max3f(mx, md, me);
    mx = fmaxf(mx, s[3][3]);
    mx = fmaxf(mx, __shfl_xor(mx, 16, 64));
    mx = fmaxf(mx, __shfl_xor(mx, 32, 64));
    if (!__all(mx - m_s <= 8.0f)) {   // T13: rescale only on real max growth
      float mnew = fmaxf(m_s, mx);
      float alpha = exp2f(m_s - mnew);
      float a4[4];
#pragma unroll
      for (int r = 0; r < 4; ++r) a4[r] = __shfl(alpha, quad * 4 + r, 16);
#pragma unroll
      for (int vt = 0; vt < 12; ++vt)
#pragma unroll
        for (int r = 0; r < 4; ++r) o[vt][r] *= a4[r];
      l_s *= alpha;
      m_s = mnew;
    }
    float p16[16];
    float ps = 0.0f;
#pragma unroll
    for (int jt = 0; jt < 4; ++jt)
#pragma unroll
      for (int r = 0; r < 4; ++r) {
        float p = exp2f(s[jt][r] - m_s);
        p16[jt * 4 + r] = p;
        ps += p;
      }
    ps += __shfl_xor(ps, 16, 64);
    ps += __shfl_xor(ps, 32, 64);
    l_s += ps;
    // ---- P -> LDS (wave-private) -> A-operand (native cvt_pk pack) ----
#pragma unroll
    for (int jt = 0; jt < 4; ++jt) {
      union { u16 h4[4]; uint2 v; } pk;
#pragma unroll
      for (int r = 0; r < 4; ++r) pk.h4[r] = f2bf_n(p16[jt * 4 + r]);
      *(uint2*)&Pl[w][l16 * 72 + jt * 16 + quad * 4] = pk.v;
    }
    asm volatile("s_waitcnt lgkmcnt(0)" ::: "memory");
    bf16x8 pf0 = *(const bf16x8*)&Pl[w][l16 * 72 + quad * 8];
    bf16x8 pf1 = *(const bf16x8*)&Pl[w][l16 * 72 + 32 + quad * 8];
    // ---- own V chunks landed (only V outstanding); barrier -> all V in,
    //      and all waves' KsL reads are done (they precede P-pack) ----
    asm volatile("s_waitcnt vmcnt(0)" ::: "memory");
    __builtin_amdgcn_s_barrier();   // (C)
    __builtin_amdgcn_sched_barrier(0);
    // ---- stage K(next tile) into KsL (safe post-C); hides under PV ----
    if (j0 + 64 < jfin) {
#pragma unroll
      for (int i = 0; i < 2; ++i) {
        int chunk = i * 256 + t;
        int j = chunk >> 3, c = (chunk & 7) ^ (j & 7);
        gl_lds16(&kbase[(size_t)(j0 + 64 + j) * 64 + c * 8],
                 &KsL[(size_t)(i * 256 + w * 64) * 8]);
      }
    }
    // ---- PV from LDS V tile ----
    __builtin_amdgcn_s_setprio(1);
#pragma unroll
    for (int vt = 0; vt < 12; ++vt) {
      int v = vt * 16 + l16;
      bf16x8 bv = *(const bf16x8*)&VsL[v * 64 + ((quad) ^ (v & 7)) * 8];
      o[vt] = mfma16(pf0, bv, o[vt]);
    }
#pragma unroll
    for (int vt = 0; vt < 12; ++vt) {
      int v = vt * 16 + l16;
      bf16x8 bv = *(const bf16x8*)&VsL[v * 64 + ((quad + 4) ^ (v & 7)) * 8];
      o[vt] = mfma16(pf1, bv, o[vt]);
    }
    __builtin_amdgcn_s_setprio(0);
    // ---- own K(j+1) landed before next barrier A ----
    asm volatile("s_waitcnt vmcnt(0)" ::: "memory");
  }

#pragma unroll
  for (int r = 0; r < 4; ++r) {
    int row = q0 + w * 16 + quad * 4 + r;
    size_t base = ((size_t)(ks * HH + h) * TT + row) * VV;
#pragma unroll
    for (int vt = 0; vt < 12; ++vt) o_part[base + vt * 16 + l16] = f2bf_n(o[vt][r]);
  }
  if (quad == 0) {
    m_part[(size_t)(ks * HH + h) * TT + q_abs] = m_s;
    l_part[(size_t)(ks * HH + h) * TT + q_abs] = l_s;
  }
}

// ---------------- combine split-K partials -> bf16 aout ----------------------
// m_part is in log2 domain -> exp2f weights.
__global__ __launch_bounds__(256) void attn_combine(
    const u16* __restrict__ o_part, const float* __restrict__ m_part,
    const float* __restrict__ l_part, u16* __restrict__ aout) {
  const int h = blockIdx.y;
  const int row = blockIdx.x * 16 + (threadIdx.x >> 4);
  const int c0 = (threadIdx.x & 15) * 12;

  float m[SPLITS], M = -3.0e38f;
#pragma unroll
  for (int s = 0; s < SPLITS; ++s) {
    m[s] = m_part[(size_t)(s * HH + h) * TT + row];
    M = fmaxf(M, m[s]);
  }
  float lsum = 0.0f, wgt[SPLITS];
#pragma unroll
  for (int s = 0; s < SPLITS; ++s) {
    wgt[s] = exp2f(m[s] - M);
    lsum += wgt[s] * l_part[(size_t)(s * HH + h) * TT + row];
  }
  float o[12];
#pragma unroll
  for (int j = 0; j < 12; ++j) o[j] = 0.0f;
#pragma unroll
  for (int s = 0; s < SPLITS; ++s) {
    const u16* op = o_part + ((size_t)(s * HH + h) * TT + row) * VV + c0;
    float wgts = wgt[s];
    uint2 u0 = *(const uint2*)&op[0];
    uint2 u1 = *(const uint2*)&op[4];
    uint2 u2 = *(const uint2*)&op[8];
    u32 uu[6] = {u0.x, u0.y, u1.x, u1.y, u2.x, u2.y};
#pragma unroll
    for (int j = 0; j < 6; ++j) {
      o[j * 2 + 0] = fmaf(wgts, bf2f((u16)(uu[j] & 0xFFFF)), o[j * 2 + 0]);
      o[j * 2 + 1] = fmaf(wgts, bf2f((u16)(uu[j] >> 16)), o[j * 2 + 1]);
    }
  }
  float inv = 1.0f / lsum;
  union { u16 hx[12]; uint2 v2[3]; } pk;
#pragma unroll
  for (int j = 0; j < 12; ++j) pk.hx[j] = f2bf(o[j] * inv);
  u16* dst = aout + (size_t)row * CC + h * VV + c0;
  *(uint2*)&dst[0] = pk.v2[0];
  *(uint2*)&dst[4] = pk.v2[1];
  *(uint2*)&dst[8] = pk.v2[2];
}

extern "C" void kernel_launch(void* const* d_in, const int* in_sizes, int n_in,
                              void* d_out, int out_size, void* d_ws, size_t ws_size,
                              hipStream_t stream) {
  (void)in_sizes; (void)n_in; (void)out_size; (void)ws_size;
  const float* x   = (const float*)d_in[0];
  const float* Wq  = (const float*)d_in[1];
  const float* Wk  = (const float*)d_in[2];
  const float* Wv  = (const float*)d_in[3];
  const float* Wr  = (const float*)d_in[4];
  const float* rwb = (const float*)d_in[5];
  const float* rrb = (const float*)d_in[6];
  const float* Wo  = (const float*)d_in[7];
  const float* bo  = (const float*)d_in[8];

  char* ws = (char*)d_ws;
  size_t off = 0;
  auto alloc = [&](size_t bytes) -> void* {
    void* p = ws + off;
    off += (bytes + 255) & ~(size_t)255;
    return p;
  };
  u16* WqT  = (u16*)alloc((size_t)512 * 1536 * 2);
  u16* WkT  = (u16*)alloc((size_t)512 * 1536 * 2);
  u16* WvT  = (u16*)alloc((size_t)1536 * 1536 * 2);
  u16* WoT  = (u16*)alloc((size_t)1536 * 1536 * 2);
  u16* xbf  = (u16*)alloc((size_t)TT * CC * 2);
  u16* qw   = (u16*)alloc((size_t)HH * TT * 64 * 2);
  u16* Kws  = (u16*)alloc((size_t)HH * TT * 64 * 2);
  u16* vTw  = (u16*)alloc((size_t)HH * VV * TT * 2);
  u16* aout = (u16*)alloc((size_t)TT * CC * 2);
  unsigned char* cidx_g = (unsigned char*)alloc(TT);
  u16* WrT      = (u16*)alloc((size_t)HH * 32 * 64 * 2);
  float* dW     = (float*)alloc((size_t)HH * 32 * 4);
  u16* o_part   = (u16*)alloc((size_t)SPLITS * HH * TT * VV * 2);
  float* m_part = (float*)alloc((size_t)SPLITS * HH * TT * 4);
  float* l_part = (float*)alloc((size_t)SPLITS * HH * TT * 4);

  prep_kernel<<<dim3(24, 24, 6), 256, 0, stream>>>(
      Wq, Wk, Wv, Wo, x, Wr, rwb, rrb,
      WqT, WkT, WvT, WoT, xbf, cidx_g, WrT, dW);
  gemm_qkv<<<dim3(40, 16), 256, 0, stream>>>(xbf, WqT, WkT, WvT,
                                             qw, Kws, vTw, rwb);
  attn_split<<<dim3(768), 256, 0, stream>>>(qw, Kws, vTw, WrT, dW, cidx_g,
                                            o_part, m_part, l_part);
  attn_combine<<<dim3(128, 8), 256, 0, stream>>>(o_part, m_part, l_part, aout);
  gemm_out<<<dim3(24, 16), 256, 0, stream>>>(aout, WoT, (float*)d_out, bo);
}